// Round 18
// baseline (215.652 us; speedup 1.0000x reference)
//
#include <hip/hip_runtime.h>
#include <hip/hip_bf16.h>
#include <math.h>

// Problem constants (from setup_inputs)
#define BB 8
#define QN 512
#define SN 64
#define TN 128
#define DD 128
#define STAT_K 8
#define TOK_K 16
#define SCALE 0.08838834764831845f   // 1/sqrt(128)
#define NEGBIG -1e6f
#define NINF  -3.4e38f

typedef float f4 __attribute__((ext_vector_type(4)));
typedef float f2 __attribute__((ext_vector_type(2)));
typedef unsigned long long u64;

// ---------------------------------------------------------------------------
// LDS-free GEMM tile, 4 rows/thread, with A-only prefetch pipeline.
// Issue order per 8-k step: W(k0) -> A(k0+4) -> FMA(aA) -> W(k0+4) ->
// A(k0+8) -> FMA(aB). vmcnt drains oldest-first, so FMA's wait covers only
// the W loads; the A prefetch rides under the 256-cyc FMA block.
// transposed: per-bin col-major store (see R11 notes).
// ---------------------------------------------------------------------------
__device__ __forceinline__ void proj_tile4_g(const float* __restrict__ A,
                                             const float* __restrict__ W,
                                             float* __restrict__ C,
                                             int rowBase, int transposed, int tid)
{
    const int tx = tid & 15;    // cols tx*4..+3 and 64+tx*4..+3
    const int ty = tid >> 4;    // 0..15, rows ty*4..+3
    const float* Ab = A + (size_t)(rowBase + ty * 4) * 128;

    float acc[4][8];
    #pragma unroll
    for (int i = 0; i < 4; ++i)
        #pragma unroll
        for (int j = 0; j < 8; ++j) acc[i][j] = 0.f;

    f4 aA[4], aB[4];
    #pragma unroll
    for (int i = 0; i < 4; ++i) aA[i] = *(const f4*)(Ab + i * 128);

    #pragma unroll 2
    for (int k0 = 0; k0 < 128; k0 += 8) {
        f4 wl[4], wh[4];
        // W(k0) first (oldest -> FMA wait covers only these)
        #pragma unroll
        for (int kk = 0; kk < 4; ++kk) {
            wl[kk] = *(const f4*)(W + (size_t)(k0 + kk) * 128 + tx * 4);
            wh[kk] = *(const f4*)(W + (size_t)(k0 + kk) * 128 + 64 + tx * 4);
        }
        // prefetch A(k0+4) (stays in flight during FMA(aA))
        #pragma unroll
        for (int i = 0; i < 4; ++i)
            aB[i] = *(const f4*)(Ab + i * 128 + k0 + 4);
        #pragma unroll
        for (int i = 0; i < 4; ++i)
            #pragma unroll
            for (int kk = 0; kk < 4; ++kk)
                #pragma unroll
                for (int j = 0; j < 4; ++j) {
                    acc[i][j]     = fmaf(aA[i][kk], wl[kk][j], acc[i][j]);
                    acc[i][4 + j] = fmaf(aA[i][kk], wh[kk][j], acc[i][4 + j]);
                }
        // W(k0+4), then prefetch A(k0+8)
        #pragma unroll
        for (int kk = 0; kk < 4; ++kk) {
            wl[kk] = *(const f4*)(W + (size_t)(k0 + 4 + kk) * 128 + tx * 4);
            wh[kk] = *(const f4*)(W + (size_t)(k0 + 4 + kk) * 128 + 64 + tx * 4);
        }
        if (k0 + 8 < 128) {
            #pragma unroll
            for (int i = 0; i < 4; ++i)
                aA[i] = *(const f4*)(Ab + i * 128 + k0 + 8);
        }
        #pragma unroll
        for (int i = 0; i < 4; ++i)
            #pragma unroll
            for (int kk = 0; kk < 4; ++kk)
                #pragma unroll
                for (int j = 0; j < 4; ++j) {
                    acc[i][j]     = fmaf(aB[i][kk], wl[kk][j], acc[i][j]);
                    acc[i][4 + j] = fmaf(aB[i][kk], wh[kk][j], acc[i][4 + j]);
                }
    }

    if (!transposed) {
        #pragma unroll
        for (int i = 0; i < 4; ++i) {
            size_t row = (size_t)rowBase + ty * 4 + i;
            f4 lo = {acc[i][0], acc[i][1], acc[i][2], acc[i][3]};
            f4 hi = {acc[i][4], acc[i][5], acc[i][6], acc[i][7]};
            *(f4*)&C[row * 128 + tx * 4]      = lo;
            *(f4*)&C[row * 128 + 64 + tx * 4] = hi;
        }
    } else {
        float* Cb = C + ((size_t)(rowBase >> 7) << 14);    // bin base
        const int rb = (rowBase & 127) + ty * 4;           // row within bin
        #pragma unroll
        for (int j = 0; j < 4; ++j) {
            int clo = tx * 4 + j;
            int chi = 64 + tx * 4 + j;
            f4 v0 = {acc[0][j], acc[1][j], acc[2][j], acc[3][j]};
            f4 v1 = {acc[0][4 + j], acc[1][4 + j], acc[2][4 + j], acc[3][4 + j]};
            *(f4*)&Cb[clo * 128 + rb] = v0;
            *(f4*)&Cb[chi * 128 + rb] = v1;
        }
    }
}

// Input projections + Wv@Wo fold + cnt zeroing, one launch, 64-row tiles.
__global__ __launch_bounds__(256) void proj_all(const float* __restrict__ queries,
                                                const float* __restrict__ stat_keys,
                                                const float* __restrict__ token_keys,
                                                const float* __restrict__ Wq_stat,
                                                const float* __restrict__ Wq_token,
                                                const float* __restrict__ Wk_stat,
                                                const float* __restrict__ Wk_token,
                                                const float* __restrict__ Wv,
                                                const float* __restrict__ Wo,
                                                float* __restrict__ q_stat,
                                                float* __restrict__ q_tok,
                                                float* __restrict__ k_stat,
                                                float* __restrict__ kT,
                                                float* __restrict__ M_vo,
                                                int* __restrict__ cnt)
{
    const int bi = blockIdx.x;
    if (bi < 1024)       proj_tile4_g(token_keys, Wk_token, kT,     bi * 64,           1, threadIdx.x);
    else if (bi < 1088)  proj_tile4_g(queries,    Wq_stat,  q_stat, (bi - 1024) * 64,  0, threadIdx.x);
    else if (bi < 1152)  proj_tile4_g(queries,    Wq_token, q_tok,  (bi - 1088) * 64,  0, threadIdx.x);
    else if (bi < 1160)  proj_tile4_g(stat_keys,  Wk_stat,  k_stat, (bi - 1152) * 64,  0, threadIdx.x);
    else if (bi < 1162)  proj_tile4_g(Wv,         Wo,       M_vo,   (bi - 1160) * 64,  0, threadIdx.x);
    else {
        for (int i = threadIdx.x; i < BB * SN; i += 256) cnt[i] = 0;
    }
}

// ---------------------------------------------------------------------------
// Stat level + binning fused (R12-proven). Unbinned (wv==0) pids get their
// pvw row zeroed here (tok_pv3 clamps stale pvt tokens).
// ---------------------------------------------------------------------------
__global__ __launch_bounds__(64, 4) void stat_topk(const float* __restrict__ qs,
                                                   const float* __restrict__ ks,
                                                   const int* __restrict__ vlen,
                                                   int* __restrict__ sel_i,
                                                   float* __restrict__ sel_w,
                                                   int* __restrict__ cnt,
                                                   int* __restrict__ list,
                                                   float* __restrict__ pvw)
{
    const int bq   = blockIdx.x;
    const int b    = bq >> 9;
    const int lane = threadIdx.x;

    const f4* q4 = (const f4*)(qs + (size_t)bq * 128);
    const f4* k4 = (const f4*)(ks + (size_t)(b * SN + lane) * 128);
    float acc = 0.f;
    #pragma unroll 8
    for (int kk = 0; kk < 32; ++kk) {
        f4 q = q4[kk];
        f4 k = k4[kk];
        acc = fmaf(q[0], k[0], acc);
        acc = fmaf(q[1], k[1], acc);
        acc = fmaf(q[2], k[2], acc);
        acc = fmaf(q[3], k[3], acc);
    }
    float score = acc * SCALE;
    if (lane >= vlen[b]) score = NEGBIG;

    float work = score;
    float tv[STAT_K];
    int   ti[STAT_K];
    #pragma unroll
    for (int j = 0; j < STAT_K; ++j) {
        float m = work;
        #pragma unroll
        for (int off = 32; off > 0; off >>= 1) m = fmaxf(m, __shfl_xor(m, off));
        unsigned long long ball = __ballot(work == m);
        int L = __ffsll(ball) - 1;     // lowest index wins ties
        tv[j] = m;
        ti[j] = L;
        if (lane == L) work = NINF;
    }

    float w[STAT_K];
    float Z = 0.f;
    #pragma unroll
    for (int j = 0; j < STAT_K; ++j) { w[j] = expf(tv[j] - tv[0]); Z += w[j]; }
    float invZ = 1.f / Z;

    if (lane < STAT_K) {
        float wv = w[lane] * invZ;
        int pid = bq * STAT_K + lane;
        sel_i[pid] = ti[lane];
        sel_w[pid] = wv;
        if (wv != 0.f) {                         // sw==0: exactly-zero contribution
            int s  = ti[lane];
            int bs = b * SN + s;
            int pos = atomicAdd(&cnt[bs], 1);
            list[bs * 512 + pos] = (bq & 511) | (lane << 16);
        } else {
            #pragma unroll
            for (int j = 0; j < TOK_K; ++j)      // never written downstream: zero
                pvw[(size_t)pid * TOK_K + j] = 0.f;
        }
    }
}

// ---------------------------------------------------------------------------
// K1 (fused): token scores + EXACT top-16 + softmax weights, all in registers.
// CHUNK=32: 2 pids per 16-lane group (acc[2][8]) -> ~2x active blocks vs R17
// (~5 waves/SIMD). Selection per round: exact fp32 group-max (4-step shfl
// fmax) + exact lowest-t tie-break via 2 ballots + 1 shfl (R17-proven).
// it-loop outer, 2 pids inner (ILP). exp hoisted out of the loop.
// ---------------------------------------------------------------------------
__global__ __launch_bounds__(256) void tok_score_sel(const float* __restrict__ qt,
                                                     const float* __restrict__ kT,
                                                     const int* __restrict__ cnt,
                                                     const int* __restrict__ list,
                                                     const float* __restrict__ sel_w,
                                                     int* __restrict__ pvt,
                                                     float* __restrict__ pvw)
{
    const int bin   = blockIdx.x & 511;
    const int chunk = blockIdx.x >> 9;   // 0..15
    const int b  = bin & 7;              // batch fast -> XCD spread
    const int s  = bin >> 3;
    const int bs = b * SN + s;
    const int nq = cnt[bs];
    const int q0 = chunk * 32;
    if (q0 >= nq) return;                // wave-uniform early out: safe

    const int tid  = threadIdx.x;
    const int tx   = tid & 15;           // token-cols
    const int ty   = tid >> 4;           // pair-slot group: pairs q0+ty*2..+1
    const int lane = tid & 63;
    const int g    = lane >> 4;          // 16-lane group within wave

    int pid[2];
    float swp[2];
    const float* Ab[2];
    #pragma unroll
    for (int i = 0; i < 2; ++i) {
        int e  = list[bs * 512 + min(q0 + ty * 2 + i, nq - 1)];  // clamp: dup pair
        int q  = e & 0xffff;
        int si = (e >> 16) & 7;
        pid[i] = ((b << 9) + q) * 8 + si;
        swp[i] = sel_w[pid[i]];
        Ab[i]  = qt + ((size_t)(b << 9) + q) * 128;
    }
    const float* kb = kT + ((size_t)bs << 14);

    float acc[2][8];
    #pragma unroll
    for (int i = 0; i < 2; ++i)
        #pragma unroll
        for (int j = 0; j < 8; ++j) acc[i][j] = 0.f;

    #pragma unroll 2
    for (int k0 = 0; k0 < 128; k0 += 4) {
        f4 a[2];
        #pragma unroll
        for (int i = 0; i < 2; ++i)
            a[i] = *(const f4*)(Ab[i] + k0);               // 16-lane broadcast
        f4 wl[4], wh[4];
        #pragma unroll
        for (int kk = 0; kk < 4; ++kk) {
            wl[kk] = *(const f4*)(kb + (size_t)(k0 + kk) * 128 + tx * 4);
            wh[kk] = *(const f4*)(kb + (size_t)(k0 + kk) * 128 + 64 + tx * 4);
        }
        #pragma unroll
        for (int i = 0; i < 2; ++i)
            #pragma unroll
            for (int kk = 0; kk < 4; ++kk)
                #pragma unroll
                for (int j = 0; j < 4; ++j) {
                    acc[i][j]     = fmaf(a[i][kk], wl[kk][j], acc[i][j]);
                    acc[i][4 + j] = fmaf(a[i][kk], wh[kk][j], acc[i][4 + j]);
                }
    }

    // ---- exact in-register top-16 + softmax, 2 pids interleaved ----
    float s8[2][8];
    #pragma unroll
    for (int i = 0; i < 2; ++i)
        #pragma unroll
        for (int j = 0; j < 8; ++j) s8[i][j] = acc[i][j] * SCALE;

    float m0[2], myM[2];
    int   myT[2];
    #pragma unroll
    for (int i = 0; i < 2; ++i) { m0[i] = 0.f; myM[i] = 0.f; myT[i] = 0; }

    for (int it = 0; it < 16; ++it) {
        #pragma unroll
        for (int i = 0; i < 2; ++i) {
            // exact fp32 group max (tree + 4-step shfl, stays in 16-lane group)
            float v01 = fmaxf(s8[i][0], s8[i][1]);
            float v23 = fmaxf(s8[i][2], s8[i][3]);
            float v45 = fmaxf(s8[i][4], s8[i][5]);
            float v67 = fmaxf(s8[i][6], s8[i][7]);
            float m = fmaxf(fmaxf(v01, v23), fmaxf(v45, v67));
            #pragma unroll
            for (int off = 8; off > 0; off >>= 1) m = fmaxf(m, __shfl_xor(m, off));

            // per-lane lowest hit slot in each half (descending scan)
            int jlo = 4, jhi = 4;                     // 4 = no hit
            #pragma unroll
            for (int j = 3; j >= 0; --j) jlo = (s8[i][j]     == m) ? j : jlo;
            #pragma unroll
            for (int j = 3; j >= 0; --j) jhi = (s8[i][4 + j] == m) ? j : jhi;

            // exact lowest-t via ballots: lower half beats upper; lowest lane
            // = lowest t (lane tx owns t = 4tx..4tx+3 / 64+4tx..64+4tx+3)
            u64 blo = __ballot(jlo < 4);
            u64 bhi = __ballot(jhi < 4);
            unsigned mlo = (unsigned)((blo >> (g * 16)) & 0xFFFFu);
            unsigned mhi = (unsigned)((bhi >> (g * 16)) & 0xFFFFu);
            bool lo = (mlo != 0);
            unsigned msel = lo ? mlo : mhi;
            int L = __ffs(msel) - 1;                  // winner lane in group
            int jsel = lo ? jlo : jhi;
            int jwin = __shfl(jsel, g * 16 + L);      // winner's slot-in-half
            int tstar = (lo ? 0 : 64) + 4 * L + jwin;

            m0[i] = (it == 0) ? m : m0[i];
            bool rec = (tx == it);
            myT[i] = rec ? tstar : myT[i];
            myM[i] = rec ? m : myM[i];

            // branch-free knock of the unique winning slot
            int slot = (lo ? 0 : 4) + jwin;           // uniform within group
            bool winlane = (tx == L);
            #pragma unroll
            for (int j = 0; j < 8; ++j)
                s8[i][j] = (winlane && slot == j) ? NINF : s8[i][j];
        }
    }

    #pragma unroll
    for (int i = 0; i < 2; ++i) {
        float myE = expf(myM[i] - m0[i]);      // exact
        float Z = myE;
        #pragma unroll
        for (int off = 8; off > 0; off >>= 1) Z += __shfl_xor(Z, off);
        float cs = swp[i] / Z;                 // fold stat weight in

        pvt[(size_t)pid[i] * TOK_K + tx] = myT[i];   // dup pids: identical data
        pvw[(size_t)pid[i] * TOK_K + tx] = myE * cs;
    }
}

// ---------------------------------------------------------------------------
// K3 (fused): PV accumulate on RAW values + output projection with M_vo.
// One wave per (b,q): PV row in registers -> LDS (same-wave, in-order) ->
// row @ M_vo (L1-resident) -> direct store to d_out. No atomics.
// t clamped to [0,127]: stale pvt for unbinned pids is harmless (pvw==0).
// ---------------------------------------------------------------------------
__global__ __launch_bounds__(256) void tok_pv3(const float* __restrict__ values,
                                               const int* __restrict__ sel_i,
                                               const int* __restrict__ pvt,
                                               const float* __restrict__ pvw,
                                               const float* __restrict__ M_vo,
                                               float* __restrict__ out)
{
    const int wid  = threadIdx.x >> 6;
    const int bq   = blockIdx.x * 4 + wid;
    const int lane = threadIdx.x & 63;
    const int b    = bq >> 9;

    float o0 = 0.f, o1 = 0.f;
    #pragma unroll
    for (int si = 0; si < STAT_K; ++si) {
        const int pid = bq * STAT_K + si;
        const int s   = sel_i[pid];
        const float* vb = values + ((size_t)(b * SN + s) << 14);
        const int*   tp = pvt + (size_t)pid * TOK_K;
        const float* wp = pvw + (size_t)pid * TOK_K;
        #pragma unroll
        for (int j = 0; j < TOK_K; ++j) {
            int   t = tp[j] & 127;           // wave-uniform; clamp stale entries
            float w = wp[j];                 // ==0 for skipped pids: exact no-op
            f2 x = *(const f2*)(vb + (size_t)t * 128 + lane * 2);
            o0 = fmaf(w, x[0], o0);
            o1 = fmaf(w, x[1], o1);
        }
    }

    __shared__ float pre[4][128];
    *(f2*)&pre[wid][lane * 2] = (f2){o0, o1};
    __asm__ __volatile__("" ::: "memory");
    __builtin_amdgcn_wave_barrier();        // same-wave LDS RAW: in-order pipe
    __asm__ __volatile__("" ::: "memory");

    float r0 = 0.f, r1 = 0.f;
    #pragma unroll 4
    for (int d = 0; d < 128; ++d) {
        float p = pre[wid][d];               // broadcast read
        f2 w = *(const f2*)(M_vo + (size_t)d * 128 + lane * 2);
        r0 = fmaf(p, w[0], r0);
        r1 = fmaf(p, w[1], r1);
    }
    *(f2*)&out[(size_t)bq * 128 + lane * 2] = (f2){r0, r1};
}

// ---------------------------------------------------------------------------
extern "C" void kernel_launch(void* const* d_in, const int* in_sizes, int n_in,
                              void* d_out, int out_size, void* d_ws, size_t ws_size,
                              hipStream_t stream)
{
    const float* queries    = (const float*)d_in[0];
    const float* stat_keys  = (const float*)d_in[1];
    const float* token_keys = (const float*)d_in[2];
    const float* values     = (const float*)d_in[3];
    const int*   vlen       = (const int*)d_in[4];
    const float* Wq_stat    = (const float*)d_in[5];
    const float* Wq_token   = (const float*)d_in[6];
    const float* Wk_stat    = (const float*)d_in[7];
    const float* Wk_token   = (const float*)d_in[8];
    const float* Wv         = (const float*)d_in[9];
    const float* Wo         = (const float*)d_in[10];

    char* ws = (char*)d_ws;
    float* q_stat  = (float*)(ws);                 // 2 MB
    float* q_tok   = (float*)(ws + 2097152);       // 2 MB
    float* k_stat  = (float*)(ws + 4194304);       // 256 KB
    float* M_vo    = (float*)(ws + 4456448);       // 64 KB (Wv @ Wo)
    int*   sel_i   = (int*)  (ws + 4521984);       // 128 KB
    float* sel_w   = (float*)(ws + 4653056);       // 128 KB
    float* kT      = (float*)(ws + 4784128);       // 32 MB
    int*   pvt     = (int*)  (ws + 38338560);      // 2 MB
    float* pvw     = (float*)(ws + 40435712);      // 2 MB
    int*   list    = (int*)  (ws + 42532864);      // 1 MB
    int*   cnt     = (int*)  (ws + 43581440);      // 2 KB   (total ~43.6 MB)

    // Projections feeding selection (fp32 exact) + Wv@Wo fold + cnt zeroing
    proj_all<<<1163, 256, 0, stream>>>(queries, stat_keys, token_keys,
                                       Wq_stat, Wq_token, Wk_stat, Wk_token, Wv, Wo,
                                       q_stat, q_tok, k_stat, kT, M_vo, cnt);

    // Stat-level top-8 + weights + bin append + pvw zeroing (fused)
    stat_topk<<<BB * QN, 64, 0, stream>>>(q_stat, k_stat, vlen, sel_i, sel_w,
                                          cnt, list, pvw);

    // K1: token scores + exact in-register top-16 + weights (chunk=32)
    tok_score_sel<<<8192, 256, 0, stream>>>(q_tok, kT, cnt, list, sel_w, pvt, pvw);

    // K3: PV + output projection fused, one wave per (b,q), direct to d_out
    tok_pv3<<<BB * QN / 4, 256, 0, stream>>>(values, sel_i, pvt, pvw, M_vo,
                                             (float*)d_out);
}

// Round 19
// 215.305 us; speedup vs baseline: 1.0016x; 1.0016x over previous
//
#include <hip/hip_runtime.h>
#include <hip/hip_bf16.h>
#include <math.h>

// Problem constants (from setup_inputs)
#define BB 8
#define QN 512
#define SN 64
#define TN 128
#define DD 128
#define STAT_K 8
#define TOK_K 16
#define SCALE 0.08838834764831845f   // 1/sqrt(128)
#define NEGBIG -1e6f
#define NINF  -3.4e38f

typedef float f4 __attribute__((ext_vector_type(4)));
typedef float f2 __attribute__((ext_vector_type(2)));
typedef unsigned long long u64;

// ---------------------------------------------------------------------------
// LDS-free GEMM tile, 4 rows/thread, with A-only prefetch pipeline (R18).
// Issue order per 8-k step: W(k0) -> A(k0+4) -> FMA(aA) -> W(k0+4) ->
// A(k0+8) -> FMA(aB). vmcnt drains oldest-first, so FMA's wait covers only
// the W loads; the A prefetch rides under the 256-cyc FMA block.
// transposed: per-bin col-major store (see R11 notes).
// ---------------------------------------------------------------------------
__device__ __forceinline__ void proj_tile4_g(const float* __restrict__ A,
                                             const float* __restrict__ W,
                                             float* __restrict__ C,
                                             int rowBase, int transposed, int tid)
{
    const int tx = tid & 15;    // cols tx*4..+3 and 64+tx*4..+3
    const int ty = tid >> 4;    // 0..15, rows ty*4..+3
    const float* Ab = A + (size_t)(rowBase + ty * 4) * 128;

    float acc[4][8];
    #pragma unroll
    for (int i = 0; i < 4; ++i)
        #pragma unroll
        for (int j = 0; j < 8; ++j) acc[i][j] = 0.f;

    f4 aA[4], aB[4];
    #pragma unroll
    for (int i = 0; i < 4; ++i) aA[i] = *(const f4*)(Ab + i * 128);

    #pragma unroll 2
    for (int k0 = 0; k0 < 128; k0 += 8) {
        f4 wl[4], wh[4];
        // W(k0) first (oldest -> FMA wait covers only these)
        #pragma unroll
        for (int kk = 0; kk < 4; ++kk) {
            wl[kk] = *(const f4*)(W + (size_t)(k0 + kk) * 128 + tx * 4);
            wh[kk] = *(const f4*)(W + (size_t)(k0 + kk) * 128 + 64 + tx * 4);
        }
        // prefetch A(k0+4) (stays in flight during FMA(aA))
        #pragma unroll
        for (int i = 0; i < 4; ++i)
            aB[i] = *(const f4*)(Ab + i * 128 + k0 + 4);
        #pragma unroll
        for (int i = 0; i < 4; ++i)
            #pragma unroll
            for (int kk = 0; kk < 4; ++kk)
                #pragma unroll
                for (int j = 0; j < 4; ++j) {
                    acc[i][j]     = fmaf(aA[i][kk], wl[kk][j], acc[i][j]);
                    acc[i][4 + j] = fmaf(aA[i][kk], wh[kk][j], acc[i][4 + j]);
                }
        // W(k0+4), then prefetch A(k0+8)
        #pragma unroll
        for (int kk = 0; kk < 4; ++kk) {
            wl[kk] = *(const f4*)(W + (size_t)(k0 + 4 + kk) * 128 + tx * 4);
            wh[kk] = *(const f4*)(W + (size_t)(k0 + 4 + kk) * 128 + 64 + tx * 4);
        }
        if (k0 + 8 < 128) {
            #pragma unroll
            for (int i = 0; i < 4; ++i)
                aA[i] = *(const f4*)(Ab + i * 128 + k0 + 8);
        }
        #pragma unroll
        for (int i = 0; i < 4; ++i)
            #pragma unroll
            for (int kk = 0; kk < 4; ++kk)
                #pragma unroll
                for (int j = 0; j < 4; ++j) {
                    acc[i][j]     = fmaf(aB[i][kk], wl[kk][j], acc[i][j]);
                    acc[i][4 + j] = fmaf(aB[i][kk], wh[kk][j], acc[i][4 + j]);
                }
    }

    if (!transposed) {
        #pragma unroll
        for (int i = 0; i < 4; ++i) {
            size_t row = (size_t)rowBase + ty * 4 + i;
            f4 lo = {acc[i][0], acc[i][1], acc[i][2], acc[i][3]};
            f4 hi = {acc[i][4], acc[i][5], acc[i][6], acc[i][7]};
            *(f4*)&C[row * 128 + tx * 4]      = lo;
            *(f4*)&C[row * 128 + 64 + tx * 4] = hi;
        }
    } else {
        float* Cb = C + ((size_t)(rowBase >> 7) << 14);    // bin base
        const int rb = (rowBase & 127) + ty * 4;           // row within bin
        #pragma unroll
        for (int j = 0; j < 4; ++j) {
            int clo = tx * 4 + j;
            int chi = 64 + tx * 4 + j;
            f4 v0 = {acc[0][j], acc[1][j], acc[2][j], acc[3][j]};
            f4 v1 = {acc[0][4 + j], acc[1][4 + j], acc[2][4 + j], acc[3][4 + j]};
            *(f4*)&Cb[clo * 128 + rb] = v0;
            *(f4*)&Cb[chi * 128 + rb] = v1;
        }
    }
}

// Input projections + Wv@Wo fold + cnt zeroing, one launch, 64-row tiles.
__global__ __launch_bounds__(256) void proj_all(const float* __restrict__ queries,
                                                const float* __restrict__ stat_keys,
                                                const float* __restrict__ token_keys,
                                                const float* __restrict__ Wq_stat,
                                                const float* __restrict__ Wq_token,
                                                const float* __restrict__ Wk_stat,
                                                const float* __restrict__ Wk_token,
                                                const float* __restrict__ Wv,
                                                const float* __restrict__ Wo,
                                                float* __restrict__ q_stat,
                                                float* __restrict__ q_tok,
                                                float* __restrict__ k_stat,
                                                float* __restrict__ kT,
                                                float* __restrict__ M_vo,
                                                int* __restrict__ cnt)
{
    const int bi = blockIdx.x;
    if (bi < 1024)       proj_tile4_g(token_keys, Wk_token, kT,     bi * 64,           1, threadIdx.x);
    else if (bi < 1088)  proj_tile4_g(queries,    Wq_stat,  q_stat, (bi - 1024) * 64,  0, threadIdx.x);
    else if (bi < 1152)  proj_tile4_g(queries,    Wq_token, q_tok,  (bi - 1088) * 64,  0, threadIdx.x);
    else if (bi < 1160)  proj_tile4_g(stat_keys,  Wk_stat,  k_stat, (bi - 1152) * 64,  0, threadIdx.x);
    else if (bi < 1162)  proj_tile4_g(Wv,         Wo,       M_vo,   (bi - 1160) * 64,  0, threadIdx.x);
    else {
        for (int i = threadIdx.x; i < BB * SN; i += 256) cnt[i] = 0;
    }
}

// ---------------------------------------------------------------------------
// Stat level + binning fused (R12-proven). Unbinned (wv==0) pids get their
// pvw row zeroed here (tok_pv3 clamps stale pvt tokens).
// ---------------------------------------------------------------------------
__global__ __launch_bounds__(64, 4) void stat_topk(const float* __restrict__ qs,
                                                   const float* __restrict__ ks,
                                                   const int* __restrict__ vlen,
                                                   int* __restrict__ sel_i,
                                                   float* __restrict__ sel_w,
                                                   int* __restrict__ cnt,
                                                   int* __restrict__ list,
                                                   float* __restrict__ pvw)
{
    const int bq   = blockIdx.x;
    const int b    = bq >> 9;
    const int lane = threadIdx.x;

    const f4* q4 = (const f4*)(qs + (size_t)bq * 128);
    const f4* k4 = (const f4*)(ks + (size_t)(b * SN + lane) * 128);
    float acc = 0.f;
    #pragma unroll 8
    for (int kk = 0; kk < 32; ++kk) {
        f4 q = q4[kk];
        f4 k = k4[kk];
        acc = fmaf(q[0], k[0], acc);
        acc = fmaf(q[1], k[1], acc);
        acc = fmaf(q[2], k[2], acc);
        acc = fmaf(q[3], k[3], acc);
    }
    float score = acc * SCALE;
    if (lane >= vlen[b]) score = NEGBIG;

    float work = score;
    float tv[STAT_K];
    int   ti[STAT_K];
    #pragma unroll
    for (int j = 0; j < STAT_K; ++j) {
        float m = work;
        #pragma unroll
        for (int off = 32; off > 0; off >>= 1) m = fmaxf(m, __shfl_xor(m, off));
        unsigned long long ball = __ballot(work == m);
        int L = __ffsll(ball) - 1;     // lowest index wins ties
        tv[j] = m;
        ti[j] = L;
        if (lane == L) work = NINF;
    }

    float w[STAT_K];
    float Z = 0.f;
    #pragma unroll
    for (int j = 0; j < STAT_K; ++j) { w[j] = expf(tv[j] - tv[0]); Z += w[j]; }
    float invZ = 1.f / Z;

    if (lane < STAT_K) {
        float wv = w[lane] * invZ;
        int pid = bq * STAT_K + lane;
        sel_i[pid] = ti[lane];
        sel_w[pid] = wv;
        if (wv != 0.f) {                         // sw==0: exactly-zero contribution
            int s  = ti[lane];
            int bs = b * SN + s;
            int pos = atomicAdd(&cnt[bs], 1);
            list[bs * 512 + pos] = (bq & 511) | (lane << 16);
        } else {
            #pragma unroll
            for (int j = 0; j < TOK_K; ++j)      // never written downstream: zero
                pvw[(size_t)pid * TOK_K + j] = 0.f;
        }
    }
}

// ---------------------------------------------------------------------------
// K1 (fused): token scores + EXACT top-16 + softmax weights, all in registers.
// 4 pids per 16-lane group (chunk=64, best FMA:load ratio — R17) with the
// R18-proven W-first/A-prefetch pipeline in the GEMM loop: the pre-FMA vmcnt
// covers only the aged W loads while the next batch rides under the FMA block.
// Selection: exact fp32 group-max + exact lowest-t via 2 ballots + 1 shfl
// (R17-proven, bit-identical results). it-loop outer, 4 pids inner (ILP).
// ---------------------------------------------------------------------------
__global__ __launch_bounds__(256) void tok_score_sel(const float* __restrict__ qt,
                                                     const float* __restrict__ kT,
                                                     const int* __restrict__ cnt,
                                                     const int* __restrict__ list,
                                                     const float* __restrict__ sel_w,
                                                     int* __restrict__ pvt,
                                                     float* __restrict__ pvw)
{
    const int bin   = blockIdx.x & 511;
    const int chunk = blockIdx.x >> 9;   // 0..7
    const int b  = bin & 7;              // batch fast -> XCD spread
    const int s  = bin >> 3;
    const int bs = b * SN + s;
    const int nq = cnt[bs];
    const int q0 = chunk * 64;
    if (q0 >= nq) return;                // wave-uniform early out: safe

    const int tid  = threadIdx.x;
    const int tx   = tid & 15;           // token-cols
    const int ty   = tid >> 4;           // pair-slots q0+ty*4..+3
    const int lane = tid & 63;
    const int g    = lane >> 4;          // 16-lane group within wave

    int pid[4];
    float swp[4];
    const float* Ab[4];
    #pragma unroll
    for (int i = 0; i < 4; ++i) {
        int e  = list[bs * 512 + min(q0 + ty * 4 + i, nq - 1)];  // clamp: dup pair
        int q  = e & 0xffff;
        int si = (e >> 16) & 7;
        pid[i] = ((b << 9) + q) * 8 + si;
        swp[i] = sel_w[pid[i]];
        Ab[i]  = qt + ((size_t)(b << 9) + q) * 128;
    }
    const float* kb = kT + ((size_t)bs << 14);

    float acc[4][8];
    #pragma unroll
    for (int i = 0; i < 4; ++i)
        #pragma unroll
        for (int j = 0; j < 8; ++j) acc[i][j] = 0.f;

    f4 aA[4], aB[4];
    #pragma unroll
    for (int i = 0; i < 4; ++i) aA[i] = *(const f4*)(Ab[i]);

    #pragma unroll 2
    for (int k0 = 0; k0 < 128; k0 += 8) {
        f4 wl[4], wh[4];
        // W(k0) first (oldest -> FMA wait covers only these)
        #pragma unroll
        for (int kk = 0; kk < 4; ++kk) {
            wl[kk] = *(const f4*)(kb + (size_t)(k0 + kk) * 128 + tx * 4);
            wh[kk] = *(const f4*)(kb + (size_t)(k0 + kk) * 128 + 64 + tx * 4);
        }
        // prefetch A(k0+4)
        #pragma unroll
        for (int i = 0; i < 4; ++i)
            aB[i] = *(const f4*)(Ab[i] + k0 + 4);
        #pragma unroll
        for (int i = 0; i < 4; ++i)
            #pragma unroll
            for (int kk = 0; kk < 4; ++kk)
                #pragma unroll
                for (int j = 0; j < 4; ++j) {
                    acc[i][j]     = fmaf(aA[i][kk], wl[kk][j], acc[i][j]);
                    acc[i][4 + j] = fmaf(aA[i][kk], wh[kk][j], acc[i][4 + j]);
                }
        // W(k0+4), then prefetch A(k0+8)
        #pragma unroll
        for (int kk = 0; kk < 4; ++kk) {
            wl[kk] = *(const f4*)(kb + (size_t)(k0 + 4 + kk) * 128 + tx * 4);
            wh[kk] = *(const f4*)(kb + (size_t)(k0 + 4 + kk) * 128 + 64 + tx * 4);
        }
        if (k0 + 8 < 128) {
            #pragma unroll
            for (int i = 0; i < 4; ++i)
                aA[i] = *(const f4*)(Ab[i] + k0 + 8);
        }
        #pragma unroll
        for (int i = 0; i < 4; ++i)
            #pragma unroll
            for (int kk = 0; kk < 4; ++kk)
                #pragma unroll
                for (int j = 0; j < 4; ++j) {
                    acc[i][j]     = fmaf(aB[i][kk], wl[kk][j], acc[i][j]);
                    acc[i][4 + j] = fmaf(aB[i][kk], wh[kk][j], acc[i][4 + j]);
                }
    }

    // ---- exact in-register top-16 + softmax, 4 pids interleaved ----
    float s8[4][8];
    #pragma unroll
    for (int i = 0; i < 4; ++i)
        #pragma unroll
        for (int j = 0; j < 8; ++j) s8[i][j] = acc[i][j] * SCALE;

    float m0[4], myM[4];
    int   myT[4];
    #pragma unroll
    for (int i = 0; i < 4; ++i) { m0[i] = 0.f; myM[i] = 0.f; myT[i] = 0; }

    for (int it = 0; it < 16; ++it) {
        #pragma unroll
        for (int i = 0; i < 4; ++i) {
            // exact fp32 group max (tree + 4-step shfl, stays in 16-lane group)
            float v01 = fmaxf(s8[i][0], s8[i][1]);
            float v23 = fmaxf(s8[i][2], s8[i][3]);
            float v45 = fmaxf(s8[i][4], s8[i][5]);
            float v67 = fmaxf(s8[i][6], s8[i][7]);
            float m = fmaxf(fmaxf(v01, v23), fmaxf(v45, v67));
            #pragma unroll
            for (int off = 8; off > 0; off >>= 1) m = fmaxf(m, __shfl_xor(m, off));

            // per-lane lowest hit slot in each half (descending scan)
            int jlo = 4, jhi = 4;                     // 4 = no hit
            #pragma unroll
            for (int j = 3; j >= 0; --j) jlo = (s8[i][j]     == m) ? j : jlo;
            #pragma unroll
            for (int j = 3; j >= 0; --j) jhi = (s8[i][4 + j] == m) ? j : jhi;

            // exact lowest-t via ballots: lower half beats upper; lowest lane
            // = lowest t (lane tx owns t = 4tx..4tx+3 / 64+4tx..64+4tx+3)
            u64 blo = __ballot(jlo < 4);
            u64 bhi = __ballot(jhi < 4);
            unsigned mlo = (unsigned)((blo >> (g * 16)) & 0xFFFFu);
            unsigned mhi = (unsigned)((bhi >> (g * 16)) & 0xFFFFu);
            bool lo = (mlo != 0);
            unsigned msel = lo ? mlo : mhi;
            int L = __ffs(msel) - 1;                  // winner lane in group
            int jsel = lo ? jlo : jhi;
            int jwin = __shfl(jsel, g * 16 + L);      // winner's slot-in-half
            int tstar = (lo ? 0 : 64) + 4 * L + jwin;

            m0[i] = (it == 0) ? m : m0[i];
            bool rec = (tx == it);
            myT[i] = rec ? tstar : myT[i];
            myM[i] = rec ? m : myM[i];

            // branch-free knock of the unique winning slot
            int slot = (lo ? 0 : 4) + jwin;           // uniform within group
            bool winlane = (tx == L);
            #pragma unroll
            for (int j = 0; j < 8; ++j)
                s8[i][j] = (winlane && slot == j) ? NINF : s8[i][j];
        }
    }

    #pragma unroll
    for (int i = 0; i < 4; ++i) {
        float myE = expf(myM[i] - m0[i]);      // exact
        float Z = myE;
        #pragma unroll
        for (int off = 8; off > 0; off >>= 1) Z += __shfl_xor(Z, off);
        float cs = swp[i] / Z;                 // fold stat weight in

        pvt[(size_t)pid[i] * TOK_K + tx] = myT[i];   // dup pids: identical data
        pvw[(size_t)pid[i] * TOK_K + tx] = myE * cs;
    }
}

// ---------------------------------------------------------------------------
// K3 (fused): PV accumulate on RAW values + output projection with M_vo.
// One wave per (b,q): PV row in registers -> LDS (same-wave, in-order) ->
// row @ M_vo (L1-resident) -> direct store to d_out. No atomics.
// t clamped to [0,127]: stale pvt for unbinned pids is harmless (pvw==0).
// ---------------------------------------------------------------------------
__global__ __launch_bounds__(256) void tok_pv3(const float* __restrict__ values,
                                               const int* __restrict__ sel_i,
                                               const int* __restrict__ pvt,
                                               const float* __restrict__ pvw,
                                               const float* __restrict__ M_vo,
                                               float* __restrict__ out)
{
    const int wid  = threadIdx.x >> 6;
    const int bq   = blockIdx.x * 4 + wid;
    const int lane = threadIdx.x & 63;
    const int b    = bq >> 9;

    float o0 = 0.f, o1 = 0.f;
    #pragma unroll
    for (int si = 0; si < STAT_K; ++si) {
        const int pid = bq * STAT_K + si;
        const int s   = sel_i[pid];
        const float* vb = values + ((size_t)(b * SN + s) << 14);
        const int*   tp = pvt + (size_t)pid * TOK_K;
        const float* wp = pvw + (size_t)pid * TOK_K;
        #pragma unroll
        for (int j = 0; j < TOK_K; ++j) {
            int   t = tp[j] & 127;           // wave-uniform; clamp stale entries
            float w = wp[j];                 // ==0 for skipped pids: exact no-op
            f2 x = *(const f2*)(vb + (size_t)t * 128 + lane * 2);
            o0 = fmaf(w, x[0], o0);
            o1 = fmaf(w, x[1], o1);
        }
    }

    __shared__ float pre[4][128];
    *(f2*)&pre[wid][lane * 2] = (f2){o0, o1};
    __asm__ __volatile__("" ::: "memory");
    __builtin_amdgcn_wave_barrier();        // same-wave LDS RAW: in-order pipe
    __asm__ __volatile__("" ::: "memory");

    float r0 = 0.f, r1 = 0.f;
    #pragma unroll 4
    for (int d = 0; d < 128; ++d) {
        float p = pre[wid][d];               // broadcast read
        f2 w = *(const f2*)(M_vo + (size_t)d * 128 + lane * 2);
        r0 = fmaf(p, w[0], r0);
        r1 = fmaf(p, w[1], r1);
    }
    *(f2*)&out[(size_t)bq * 128 + lane * 2] = (f2){r0, r1};
}

// ---------------------------------------------------------------------------
extern "C" void kernel_launch(void* const* d_in, const int* in_sizes, int n_in,
                              void* d_out, int out_size, void* d_ws, size_t ws_size,
                              hipStream_t stream)
{
    const float* queries    = (const float*)d_in[0];
    const float* stat_keys  = (const float*)d_in[1];
    const float* token_keys = (const float*)d_in[2];
    const float* values     = (const float*)d_in[3];
    const int*   vlen       = (const int*)d_in[4];
    const float* Wq_stat    = (const float*)d_in[5];
    const float* Wq_token   = (const float*)d_in[6];
    const float* Wk_stat    = (const float*)d_in[7];
    const float* Wk_token   = (const float*)d_in[8];
    const float* Wv         = (const float*)d_in[9];
    const float* Wo         = (const float*)d_in[10];

    char* ws = (char*)d_ws;
    float* q_stat  = (float*)(ws);                 // 2 MB
    float* q_tok   = (float*)(ws + 2097152);       // 2 MB
    float* k_stat  = (float*)(ws + 4194304);       // 256 KB
    float* M_vo    = (float*)(ws + 4456448);       // 64 KB (Wv @ Wo)
    int*   sel_i   = (int*)  (ws + 4521984);       // 128 KB
    float* sel_w   = (float*)(ws + 4653056);       // 128 KB
    float* kT      = (float*)(ws + 4784128);       // 32 MB
    int*   pvt     = (int*)  (ws + 38338560);      // 2 MB
    float* pvw     = (float*)(ws + 40435712);      // 2 MB
    int*   list    = (int*)  (ws + 42532864);      // 1 MB
    int*   cnt     = (int*)  (ws + 43581440);      // 2 KB   (total ~43.6 MB)

    // Projections feeding selection (fp32 exact) + Wv@Wo fold + cnt zeroing
    proj_all<<<1163, 256, 0, stream>>>(queries, stat_keys, token_keys,
                                       Wq_stat, Wq_token, Wk_stat, Wk_token, Wv, Wo,
                                       q_stat, q_tok, k_stat, kT, M_vo, cnt);

    // Stat-level top-8 + weights + bin append + pvw zeroing (fused)
    stat_topk<<<BB * QN, 64, 0, stream>>>(q_stat, k_stat, vlen, sel_i, sel_w,
                                          cnt, list, pvw);

    // K1: token scores + exact in-register top-16 + weights (chunk=64,
    // 4 pids/group, pipelined GEMM)
    tok_score_sel<<<4096, 256, 0, stream>>>(q_tok, kT, cnt, list, sel_w, pvt, pvw);

    // K3: PV + output projection fused, one wave per (b,q), direct to d_out
    tok_pv3<<<BB * QN / 4, 256, 0, stream>>>(values, sel_i, pvt, pvw, M_vo,
                                             (float*)d_out);
}

// Round 20
// 198.289 us; speedup vs baseline: 1.0876x; 1.0858x over previous
//
#include <hip/hip_runtime.h>
#include <hip/hip_bf16.h>
#include <math.h>

// Problem constants (from setup_inputs)
#define BB 8
#define QN 512
#define SN 64
#define TN 128
#define DD 128
#define STAT_K 8
#define TOK_K 16
#define SCALE 0.08838834764831845f   // 1/sqrt(128)
#define NEGBIG -1e6f
#define NINF  -3.4e38f

typedef float f4 __attribute__((ext_vector_type(4)));
typedef float f2 __attribute__((ext_vector_type(2)));
typedef unsigned long long u64;

// ---------------------------------------------------------------------------
// LDS-free GEMM tile, 4 rows/thread (64-row blocks, 256 threads, acc[4][8]).
// R17-proven exact form (82 us for proj_all at 211.5 total — the anchor).
// transposed: per-bin col-major store (see R11 notes).
// ---------------------------------------------------------------------------
__device__ __forceinline__ void proj_tile4_g(const float* __restrict__ A,
                                             const float* __restrict__ W,
                                             float* __restrict__ C,
                                             int rowBase, int transposed, int tid)
{
    const int tx = tid & 15;    // cols tx*4..+3 and 64+tx*4..+3
    const int ty = tid >> 4;    // 0..15, rows ty*4..+3
    const float* Ab = A + (size_t)(rowBase + ty * 4) * 128;

    float acc[4][8];
    #pragma unroll
    for (int i = 0; i < 4; ++i)
        #pragma unroll
        for (int j = 0; j < 8; ++j) acc[i][j] = 0.f;

    #pragma unroll 2
    for (int k0 = 0; k0 < 128; k0 += 4) {
        f4 a[4];
        #pragma unroll
        for (int i = 0; i < 4; ++i)
            a[i] = *(const f4*)(Ab + i * 128 + k0);        // 16-lane broadcast
        f4 wl[4], wh[4];
        #pragma unroll
        for (int kk = 0; kk < 4; ++kk) {
            wl[kk] = *(const f4*)(W + (size_t)(k0 + kk) * 128 + tx * 4);
            wh[kk] = *(const f4*)(W + (size_t)(k0 + kk) * 128 + 64 + tx * 4);
        }
        #pragma unroll
        for (int i = 0; i < 4; ++i)
            #pragma unroll
            for (int kk = 0; kk < 4; ++kk)
                #pragma unroll
                for (int j = 0; j < 4; ++j) {
                    acc[i][j]     = fmaf(a[i][kk], wl[kk][j], acc[i][j]);
                    acc[i][4 + j] = fmaf(a[i][kk], wh[kk][j], acc[i][4 + j]);
                }
    }

    if (!transposed) {
        #pragma unroll
        for (int i = 0; i < 4; ++i) {
            size_t row = (size_t)rowBase + ty * 4 + i;
            f4 lo = {acc[i][0], acc[i][1], acc[i][2], acc[i][3]};
            f4 hi = {acc[i][4], acc[i][5], acc[i][6], acc[i][7]};
            *(f4*)&C[row * 128 + tx * 4]      = lo;
            *(f4*)&C[row * 128 + 64 + tx * 4] = hi;
        }
    } else {
        float* Cb = C + ((size_t)(rowBase >> 7) << 14);    // bin base
        const int rb = (rowBase & 127) + ty * 4;           // row within bin
        #pragma unroll
        for (int j = 0; j < 4; ++j) {
            int clo = tx * 4 + j;
            int chi = 64 + tx * 4 + j;
            f4 v0 = {acc[0][j], acc[1][j], acc[2][j], acc[3][j]};
            f4 v1 = {acc[0][4 + j], acc[1][4 + j], acc[2][4 + j], acc[3][4 + j]};
            *(f4*)&Cb[clo * 128 + rb] = v0;
            *(f4*)&Cb[chi * 128 + rb] = v1;
        }
    }
}

// Input projections + Wv@Wo fold + cnt zeroing, one launch, 64-row tiles.
__global__ __launch_bounds__(256) void proj_all(const float* __restrict__ queries,
                                                const float* __restrict__ stat_keys,
                                                const float* __restrict__ token_keys,
                                                const float* __restrict__ Wq_stat,
                                                const float* __restrict__ Wq_token,
                                                const float* __restrict__ Wk_stat,
                                                const float* __restrict__ Wk_token,
                                                const float* __restrict__ Wv,
                                                const float* __restrict__ Wo,
                                                float* __restrict__ q_stat,
                                                float* __restrict__ q_tok,
                                                float* __restrict__ k_stat,
                                                float* __restrict__ kT,
                                                float* __restrict__ M_vo,
                                                int* __restrict__ cnt)
{
    const int bi = blockIdx.x;
    if (bi < 1024)       proj_tile4_g(token_keys, Wk_token, kT,     bi * 64,           1, threadIdx.x);
    else if (bi < 1088)  proj_tile4_g(queries,    Wq_stat,  q_stat, (bi - 1024) * 64,  0, threadIdx.x);
    else if (bi < 1152)  proj_tile4_g(queries,    Wq_token, q_tok,  (bi - 1088) * 64,  0, threadIdx.x);
    else if (bi < 1160)  proj_tile4_g(stat_keys,  Wk_stat,  k_stat, (bi - 1152) * 64,  0, threadIdx.x);
    else if (bi < 1162)  proj_tile4_g(Wv,         Wo,       M_vo,   (bi - 1160) * 64,  0, threadIdx.x);
    else {
        for (int i = threadIdx.x; i < BB * SN; i += 256) cnt[i] = 0;
    }
}

// ---------------------------------------------------------------------------
// Stat level + binning fused (R12-proven). Unbinned (wv==0) pids get their
// pvw row zeroed here (tok_pv3 clamps stale pvt tokens).
// ---------------------------------------------------------------------------
__global__ __launch_bounds__(64, 4) void stat_topk(const float* __restrict__ qs,
                                                   const float* __restrict__ ks,
                                                   const int* __restrict__ vlen,
                                                   int* __restrict__ sel_i,
                                                   float* __restrict__ sel_w,
                                                   int* __restrict__ cnt,
                                                   int* __restrict__ list,
                                                   float* __restrict__ pvw)
{
    const int bq   = blockIdx.x;
    const int b    = bq >> 9;
    const int lane = threadIdx.x;

    const f4* q4 = (const f4*)(qs + (size_t)bq * 128);
    const f4* k4 = (const f4*)(ks + (size_t)(b * SN + lane) * 128);
    float acc = 0.f;
    #pragma unroll 8
    for (int kk = 0; kk < 32; ++kk) {
        f4 q = q4[kk];
        f4 k = k4[kk];
        acc = fmaf(q[0], k[0], acc);
        acc = fmaf(q[1], k[1], acc);
        acc = fmaf(q[2], k[2], acc);
        acc = fmaf(q[3], k[3], acc);
    }
    float score = acc * SCALE;
    if (lane >= vlen[b]) score = NEGBIG;

    float work = score;
    float tv[STAT_K];
    int   ti[STAT_K];
    #pragma unroll
    for (int j = 0; j < STAT_K; ++j) {
        float m = work;
        #pragma unroll
        for (int off = 32; off > 0; off >>= 1) m = fmaxf(m, __shfl_xor(m, off));
        unsigned long long ball = __ballot(work == m);
        int L = __ffsll(ball) - 1;     // lowest index wins ties
        tv[j] = m;
        ti[j] = L;
        if (lane == L) work = NINF;
    }

    float w[STAT_K];
    float Z = 0.f;
    #pragma unroll
    for (int j = 0; j < STAT_K; ++j) { w[j] = expf(tv[j] - tv[0]); Z += w[j]; }
    float invZ = 1.f / Z;

    if (lane < STAT_K) {
        float wv = w[lane] * invZ;
        int pid = bq * STAT_K + lane;
        sel_i[pid] = ti[lane];
        sel_w[pid] = wv;
        if (wv != 0.f) {                         // sw==0: exactly-zero contribution
            int s  = ti[lane];
            int bs = b * SN + s;
            int pos = atomicAdd(&cnt[bs], 1);
            list[bs * 512 + pos] = (bq & 511) | (lane << 16);
        } else {
            #pragma unroll
            for (int j = 0; j < TOK_K; ++j)      // never written downstream: zero
                pvw[(size_t)pid * TOK_K + j] = 0.f;
        }
    }
}

// ---------------------------------------------------------------------------
// K1 (fused): token scores + EXACT top-16 + softmax weights.
// NEW: the bin's k-block is staged in LDS in two 32 KB halves (d in [0,64),
// [64,128)) -> W-reads become ds_read_b128 (12-cyc throughput, 2-way alias =
// free, 4 lane-groups broadcast) instead of 250-cyc L2 streams. 32 KB LDS ->
// 4 blocks/CU = 16 waves/CU. Early-exit is block-uniform -> barrier-safe.
// Selection: R17-proven exact path, byte-identical results.
// ---------------------------------------------------------------------------
__global__ __launch_bounds__(256) void tok_score_sel(const float* __restrict__ qt,
                                                     const float* __restrict__ kT,
                                                     const int* __restrict__ cnt,
                                                     const int* __restrict__ list,
                                                     const float* __restrict__ sel_w,
                                                     int* __restrict__ pvt,
                                                     float* __restrict__ pvw)
{
    const int bin   = blockIdx.x & 511;
    const int chunk = blockIdx.x >> 9;   // 0..7
    const int b  = bin & 7;              // batch fast -> XCD spread
    const int s  = bin >> 3;
    const int bs = b * SN + s;
    const int nq = cnt[bs];
    const int q0 = chunk * 64;
    if (q0 >= nq) return;                // block-uniform early out (pre-barrier)

    const int tid  = threadIdx.x;
    const int tx   = tid & 15;           // token-cols
    const int ty   = tid >> 4;           // pair-slots q0+ty*4..+3
    const int lane = tid & 63;
    const int g    = lane >> 4;          // 16-lane group within wave

    int pid[4];
    float swp[4];
    const float* Ab[4];
    #pragma unroll
    for (int i = 0; i < 4; ++i) {
        int e  = list[bs * 512 + min(q0 + ty * 4 + i, nq - 1)];  // clamp: dup pair
        int q  = e & 0xffff;
        int si = (e >> 16) & 7;
        pid[i] = ((b << 9) + q) * 8 + si;
        swp[i] = sel_w[pid[i]];
        Ab[i]  = qt + ((size_t)(b << 9) + q) * 128;
    }
    const float* kb = kT + ((size_t)bs << 14);

    __shared__ float ksh[64 * 128];      // 32 KB: one d-half of the k-block

    float acc[4][8];
    #pragma unroll
    for (int i = 0; i < 4; ++i)
        #pragma unroll
        for (int j = 0; j < 8; ++j) acc[i][j] = 0.f;

    for (int h = 0; h < 2; ++h) {
        // stage half h: 64 rows x 128 cols = 2048 f4, 8 per thread
        const f4* src = (const f4*)(kb + (size_t)h * 64 * 128);
        __syncthreads();                 // protect prior-half reads
        #pragma unroll
        for (int it2 = 0; it2 < 8; ++it2)
            ((f4*)ksh)[it2 * 256 + tid] = src[it2 * 256 + tid];
        __syncthreads();

        #pragma unroll 2
        for (int k0 = 0; k0 < 64; k0 += 4) {
            f4 a[4];
            #pragma unroll
            for (int i = 0; i < 4; ++i)
                a[i] = *(const f4*)(Ab[i] + h * 64 + k0);  // 16-lane broadcast
            f4 wl[4], wh[4];
            #pragma unroll
            for (int kk = 0; kk < 4; ++kk) {
                wl[kk] = *(const f4*)&ksh[(k0 + kk) * 128 + tx * 4];
                wh[kk] = *(const f4*)&ksh[(k0 + kk) * 128 + 64 + tx * 4];
            }
            #pragma unroll
            for (int i = 0; i < 4; ++i)
                #pragma unroll
                for (int kk = 0; kk < 4; ++kk)
                    #pragma unroll
                    for (int j = 0; j < 4; ++j) {
                        acc[i][j]     = fmaf(a[i][kk], wl[kk][j], acc[i][j]);
                        acc[i][4 + j] = fmaf(a[i][kk], wh[kk][j], acc[i][4 + j]);
                    }
        }
    }

    // ---- exact in-register top-16 + softmax, 4 pids interleaved (R17) ----
    float s8[4][8];
    #pragma unroll
    for (int i = 0; i < 4; ++i)
        #pragma unroll
        for (int j = 0; j < 8; ++j) s8[i][j] = acc[i][j] * SCALE;

    float m0[4], myM[4];
    int   myT[4];
    #pragma unroll
    for (int i = 0; i < 4; ++i) { m0[i] = 0.f; myM[i] = 0.f; myT[i] = 0; }

    for (int it = 0; it < 16; ++it) {
        #pragma unroll
        for (int i = 0; i < 4; ++i) {
            // exact fp32 group max (tree + 4-step shfl, stays in 16-lane group)
            float v01 = fmaxf(s8[i][0], s8[i][1]);
            float v23 = fmaxf(s8[i][2], s8[i][3]);
            float v45 = fmaxf(s8[i][4], s8[i][5]);
            float v67 = fmaxf(s8[i][6], s8[i][7]);
            float m = fmaxf(fmaxf(v01, v23), fmaxf(v45, v67));
            #pragma unroll
            for (int off = 8; off > 0; off >>= 1) m = fmaxf(m, __shfl_xor(m, off));

            // per-lane lowest hit slot in each half (descending scan)
            int jlo = 4, jhi = 4;                     // 4 = no hit
            #pragma unroll
            for (int j = 3; j >= 0; --j) jlo = (s8[i][j]     == m) ? j : jlo;
            #pragma unroll
            for (int j = 3; j >= 0; --j) jhi = (s8[i][4 + j] == m) ? j : jhi;

            // exact lowest-t via ballots: lower half beats upper; lowest lane
            // = lowest t (lane tx owns t = 4tx..4tx+3 / 64+4tx..64+4tx+3)
            u64 blo = __ballot(jlo < 4);
            u64 bhi = __ballot(jhi < 4);
            unsigned mlo = (unsigned)((blo >> (g * 16)) & 0xFFFFu);
            unsigned mhi = (unsigned)((bhi >> (g * 16)) & 0xFFFFu);
            bool lo = (mlo != 0);
            unsigned msel = lo ? mlo : mhi;
            int L = __ffs(msel) - 1;                  // winner lane in group
            int jsel = lo ? jlo : jhi;
            int jwin = __shfl(jsel, g * 16 + L);      // winner's slot-in-half
            int tstar = (lo ? 0 : 64) + 4 * L + jwin;

            m0[i] = (it == 0) ? m : m0[i];
            bool rec = (tx == it);
            myT[i] = rec ? tstar : myT[i];
            myM[i] = rec ? m : myM[i];

            // branch-free knock of the unique winning slot
            int slot = (lo ? 0 : 4) + jwin;           // uniform within group
            bool winlane = (tx == L);
            #pragma unroll
            for (int j = 0; j < 8; ++j)
                s8[i][j] = (winlane && slot == j) ? NINF : s8[i][j];
        }
    }

    #pragma unroll
    for (int i = 0; i < 4; ++i) {
        float myE = expf(myM[i] - m0[i]);      // exact
        float Z = myE;
        #pragma unroll
        for (int off = 8; off > 0; off >>= 1) Z += __shfl_xor(Z, off);
        float cs = swp[i] / Z;                 // fold stat weight in

        pvt[(size_t)pid[i] * TOK_K + tx] = myT[i];   // dup pids: identical data
        pvw[(size_t)pid[i] * TOK_K + tx] = myE * cs;
    }
}

// ---------------------------------------------------------------------------
// K3 (fused): PV accumulate on RAW values + output projection with M_vo.
// One wave per (b,q): PV row in registers -> LDS (same-wave, in-order) ->
// row @ M_vo (L1-resident) -> direct store to d_out. No atomics.
// t clamped to [0,127]: stale pvt for unbinned pids is harmless (pvw==0).
// ---------------------------------------------------------------------------
__global__ __launch_bounds__(256) void tok_pv3(const float* __restrict__ values,
                                               const int* __restrict__ sel_i,
                                               const int* __restrict__ pvt,
                                               const float* __restrict__ pvw,
                                               const float* __restrict__ M_vo,
                                               float* __restrict__ out)
{
    const int wid  = threadIdx.x >> 6;
    const int bq   = blockIdx.x * 4 + wid;
    const int lane = threadIdx.x & 63;
    const int b    = bq >> 9;

    float o0 = 0.f, o1 = 0.f;
    #pragma unroll
    for (int si = 0; si < STAT_K; ++si) {
        const int pid = bq * STAT_K + si;
        const int s   = sel_i[pid];
        const float* vb = values + ((size_t)(b * SN + s) << 14);
        const int*   tp = pvt + (size_t)pid * TOK_K;
        const float* wp = pvw + (size_t)pid * TOK_K;
        #pragma unroll
        for (int j = 0; j < TOK_K; ++j) {
            int   t = tp[j] & 127;           // wave-uniform; clamp stale entries
            float w = wp[j];                 // ==0 for skipped pids: exact no-op
            f2 x = *(const f2*)(vb + (size_t)t * 128 + lane * 2);
            o0 = fmaf(w, x[0], o0);
            o1 = fmaf(w, x[1], o1);
        }
    }

    __shared__ float pre[4][128];
    *(f2*)&pre[wid][lane * 2] = (f2){o0, o1};
    __asm__ __volatile__("" ::: "memory");
    __builtin_amdgcn_wave_barrier();        // same-wave LDS RAW: in-order pipe
    __asm__ __volatile__("" ::: "memory");

    float r0 = 0.f, r1 = 0.f;
    #pragma unroll 4
    for (int d = 0; d < 128; ++d) {
        float p = pre[wid][d];               // broadcast read
        f2 w = *(const f2*)(M_vo + (size_t)d * 128 + lane * 2);
        r0 = fmaf(p, w[0], r0);
        r1 = fmaf(p, w[1], r1);
    }
    *(f2*)&out[(size_t)bq * 128 + lane * 2] = (f2){r0, r1};
}

// ---------------------------------------------------------------------------
extern "C" void kernel_launch(void* const* d_in, const int* in_sizes, int n_in,
                              void* d_out, int out_size, void* d_ws, size_t ws_size,
                              hipStream_t stream)
{
    const float* queries    = (const float*)d_in[0];
    const float* stat_keys  = (const float*)d_in[1];
    const float* token_keys = (const float*)d_in[2];
    const float* values     = (const float*)d_in[3];
    const int*   vlen       = (const int*)d_in[4];
    const float* Wq_stat    = (const float*)d_in[5];
    const float* Wq_token   = (const float*)d_in[6];
    const float* Wk_stat    = (const float*)d_in[7];
    const float* Wk_token   = (const float*)d_in[8];
    const float* Wv         = (const float*)d_in[9];
    const float* Wo         = (const float*)d_in[10];

    char* ws = (char*)d_ws;
    float* q_stat  = (float*)(ws);                 // 2 MB
    float* q_tok   = (float*)(ws + 2097152);       // 2 MB
    float* k_stat  = (float*)(ws + 4194304);       // 256 KB
    float* M_vo    = (float*)(ws + 4456448);       // 64 KB (Wv @ Wo)
    int*   sel_i   = (int*)  (ws + 4521984);       // 128 KB
    float* sel_w   = (float*)(ws + 4653056);       // 128 KB
    float* kT      = (float*)(ws + 4784128);       // 32 MB
    int*   pvt     = (int*)  (ws + 38338560);      // 2 MB
    float* pvw     = (float*)(ws + 40435712);      // 2 MB
    int*   list    = (int*)  (ws + 42532864);      // 1 MB
    int*   cnt     = (int*)  (ws + 43581440);      // 2 KB   (total ~43.6 MB)

    // Projections feeding selection (fp32 exact) + Wv@Wo fold + cnt zeroing
    proj_all<<<1163, 256, 0, stream>>>(queries, stat_keys, token_keys,
                                       Wq_stat, Wq_token, Wk_stat, Wk_token, Wv, Wo,
                                       q_stat, q_tok, k_stat, kT, M_vo, cnt);

    // Stat-level top-8 + weights + bin append + pvw zeroing (fused)
    stat_topk<<<BB * QN, 64, 0, stream>>>(q_stat, k_stat, vlen, sel_i, sel_w,
                                          cnt, list, pvw);

    // K1: token scores (k-block LDS-staged) + exact top-16 + weights
    tok_score_sel<<<4096, 256, 0, stream>>>(q_tok, kT, cnt, list, sel_w, pvt, pvw);

    // K3: PV + output projection fused, one wave per (b,q), direct to d_out
    tok_pv3<<<BB * QN / 4, 256, 0, stream>>>(values, sel_i, pvt, pvw, M_vo,
                                             (float*)d_out);
}

// Round 21
// 173.624 us; speedup vs baseline: 1.2421x; 1.1421x over previous
//
#include <hip/hip_runtime.h>
#include <hip/hip_bf16.h>
#include <math.h>

// Problem constants (from setup_inputs)
#define BB 8
#define QN 512
#define SN 64
#define TN 128
#define DD 128
#define STAT_K 8
#define TOK_K 16
#define SCALE 0.08838834764831845f   // 1/sqrt(128)
#define NEGBIG -1e6f
#define NINF  -3.4e38f

typedef float f4 __attribute__((ext_vector_type(4)));
typedef float f2 __attribute__((ext_vector_type(2)));
typedef unsigned long long u64;

// ---------------------------------------------------------------------------
// GEMM tile, 4 rows/thread, W staged in LDS in two 32 KB halves (R20-proven
// pattern from tok_score_sel): W-reads become broadcast ds_read_b128 (12-cyc,
// 2-way alias = free) instead of ~250-cyc L2 streams; A-loads (16-lane
// broadcast) ride under the 256-cyc FMA blocks. 32 KB LDS -> 4 blocks/CU.
// transposed: per-bin col-major store (see R11 notes).
// ---------------------------------------------------------------------------
__device__ __forceinline__ void proj_tile4_lds(const float* __restrict__ A,
                                               const float* __restrict__ W,
                                               float* __restrict__ C,
                                               int rowBase, int transposed,
                                               int tid, float* __restrict__ wsh)
{
    const int tx = tid & 15;    // cols tx*4..+3 and 64+tx*4..+3
    const int ty = tid >> 4;    // 0..15, rows ty*4..+3
    const float* Ab = A + (size_t)(rowBase + ty * 4) * 128;

    float acc[4][8];
    #pragma unroll
    for (int i = 0; i < 4; ++i)
        #pragma unroll
        for (int j = 0; j < 8; ++j) acc[i][j] = 0.f;

    for (int h = 0; h < 2; ++h) {
        // stage W half h: 64 k-rows x 128 cols = 2048 f4, 8 per thread
        const f4* src = (const f4*)(W + (size_t)h * 64 * 128);
        __syncthreads();                 // protect prior-half reads
        #pragma unroll
        for (int i2 = 0; i2 < 8; ++i2)
            ((f4*)wsh)[i2 * 256 + tid] = src[i2 * 256 + tid];
        __syncthreads();

        #pragma unroll 2
        for (int k0 = 0; k0 < 64; k0 += 4) {
            f4 a[4];
            #pragma unroll
            for (int i = 0; i < 4; ++i)
                a[i] = *(const f4*)(Ab + i * 128 + h * 64 + k0);  // 16-lane bcast
            f4 wl[4], wh[4];
            #pragma unroll
            for (int kk = 0; kk < 4; ++kk) {
                wl[kk] = *(const f4*)&wsh[(k0 + kk) * 128 + tx * 4];
                wh[kk] = *(const f4*)&wsh[(k0 + kk) * 128 + 64 + tx * 4];
            }
            #pragma unroll
            for (int i = 0; i < 4; ++i)
                #pragma unroll
                for (int kk = 0; kk < 4; ++kk)
                    #pragma unroll
                    for (int j = 0; j < 4; ++j) {
                        acc[i][j]     = fmaf(a[i][kk], wl[kk][j], acc[i][j]);
                        acc[i][4 + j] = fmaf(a[i][kk], wh[kk][j], acc[i][4 + j]);
                    }
        }
    }

    if (!transposed) {
        #pragma unroll
        for (int i = 0; i < 4; ++i) {
            size_t row = (size_t)rowBase + ty * 4 + i;
            f4 lo = {acc[i][0], acc[i][1], acc[i][2], acc[i][3]};
            f4 hi = {acc[i][4], acc[i][5], acc[i][6], acc[i][7]};
            *(f4*)&C[row * 128 + tx * 4]      = lo;
            *(f4*)&C[row * 128 + 64 + tx * 4] = hi;
        }
    } else {
        float* Cb = C + ((size_t)(rowBase >> 7) << 14);    // bin base
        const int rb = (rowBase & 127) + ty * 4;           // row within bin
        #pragma unroll
        for (int j = 0; j < 4; ++j) {
            int clo = tx * 4 + j;
            int chi = 64 + tx * 4 + j;
            f4 v0 = {acc[0][j], acc[1][j], acc[2][j], acc[3][j]};
            f4 v1 = {acc[0][4 + j], acc[1][4 + j], acc[2][4 + j], acc[3][4 + j]};
            *(f4*)&Cb[clo * 128 + rb] = v0;
            *(f4*)&Cb[chi * 128 + rb] = v1;
        }
    }
}

// Input projections + Wv@Wo fold + cnt zeroing, one launch, 64-row tiles.
__global__ __launch_bounds__(256) void proj_all(const float* __restrict__ queries,
                                                const float* __restrict__ stat_keys,
                                                const float* __restrict__ token_keys,
                                                const float* __restrict__ Wq_stat,
                                                const float* __restrict__ Wq_token,
                                                const float* __restrict__ Wk_stat,
                                                const float* __restrict__ Wk_token,
                                                const float* __restrict__ Wv,
                                                const float* __restrict__ Wo,
                                                float* __restrict__ q_stat,
                                                float* __restrict__ q_tok,
                                                float* __restrict__ k_stat,
                                                float* __restrict__ kT,
                                                float* __restrict__ M_vo,
                                                int* __restrict__ cnt)
{
    __shared__ float wsh[64 * 128];      // 32 KB: one k-half of W
    const int bi = blockIdx.x;
    if (bi < 1024)       proj_tile4_lds(token_keys, Wk_token, kT,     bi * 64,           1, threadIdx.x, wsh);
    else if (bi < 1088)  proj_tile4_lds(queries,    Wq_stat,  q_stat, (bi - 1024) * 64,  0, threadIdx.x, wsh);
    else if (bi < 1152)  proj_tile4_lds(queries,    Wq_token, q_tok,  (bi - 1088) * 64,  0, threadIdx.x, wsh);
    else if (bi < 1160)  proj_tile4_lds(stat_keys,  Wk_stat,  k_stat, (bi - 1152) * 64,  0, threadIdx.x, wsh);
    else if (bi < 1162)  proj_tile4_lds(Wv,         Wo,       M_vo,   (bi - 1160) * 64,  0, threadIdx.x, wsh);
    else {
        for (int i = threadIdx.x; i < BB * SN; i += 256) cnt[i] = 0;
    }
}

// ---------------------------------------------------------------------------
// Stat level + binning fused (R12-proven). Unbinned (wv==0) pids get their
// pvw row zeroed here (tok_pv3 clamps stale pvt tokens).
// ---------------------------------------------------------------------------
__global__ __launch_bounds__(64, 4) void stat_topk(const float* __restrict__ qs,
                                                   const float* __restrict__ ks,
                                                   const int* __restrict__ vlen,
                                                   int* __restrict__ sel_i,
                                                   float* __restrict__ sel_w,
                                                   int* __restrict__ cnt,
                                                   int* __restrict__ list,
                                                   float* __restrict__ pvw)
{
    const int bq   = blockIdx.x;
    const int b    = bq >> 9;
    const int lane = threadIdx.x;

    const f4* q4 = (const f4*)(qs + (size_t)bq * 128);
    const f4* k4 = (const f4*)(ks + (size_t)(b * SN + lane) * 128);
    float acc = 0.f;
    #pragma unroll 8
    for (int kk = 0; kk < 32; ++kk) {
        f4 q = q4[kk];
        f4 k = k4[kk];
        acc = fmaf(q[0], k[0], acc);
        acc = fmaf(q[1], k[1], acc);
        acc = fmaf(q[2], k[2], acc);
        acc = fmaf(q[3], k[3], acc);
    }
    float score = acc * SCALE;
    if (lane >= vlen[b]) score = NEGBIG;

    float work = score;
    float tv[STAT_K];
    int   ti[STAT_K];
    #pragma unroll
    for (int j = 0; j < STAT_K; ++j) {
        float m = work;
        #pragma unroll
        for (int off = 32; off > 0; off >>= 1) m = fmaxf(m, __shfl_xor(m, off));
        unsigned long long ball = __ballot(work == m);
        int L = __ffsll(ball) - 1;     // lowest index wins ties
        tv[j] = m;
        ti[j] = L;
        if (lane == L) work = NINF;
    }

    float w[STAT_K];
    float Z = 0.f;
    #pragma unroll
    for (int j = 0; j < STAT_K; ++j) { w[j] = expf(tv[j] - tv[0]); Z += w[j]; }
    float invZ = 1.f / Z;

    if (lane < STAT_K) {
        float wv = w[lane] * invZ;
        int pid = bq * STAT_K + lane;
        sel_i[pid] = ti[lane];
        sel_w[pid] = wv;
        if (wv != 0.f) {                         // sw==0: exactly-zero contribution
            int s  = ti[lane];
            int bs = b * SN + s;
            int pos = atomicAdd(&cnt[bs], 1);
            list[bs * 512 + pos] = (bq & 511) | (lane << 16);
        } else {
            #pragma unroll
            for (int j = 0; j < TOK_K; ++j)      // never written downstream: zero
                pvw[(size_t)pid * TOK_K + j] = 0.f;
        }
    }
}

// ---------------------------------------------------------------------------
// K1 (fused): token scores + EXACT top-16 + softmax weights. k-block staged
// in LDS in two 32 KB halves (R20-proven). Selection: R17-proven exact path.
// ---------------------------------------------------------------------------
__global__ __launch_bounds__(256) void tok_score_sel(const float* __restrict__ qt,
                                                     const float* __restrict__ kT,
                                                     const int* __restrict__ cnt,
                                                     const int* __restrict__ list,
                                                     const float* __restrict__ sel_w,
                                                     int* __restrict__ pvt,
                                                     float* __restrict__ pvw)
{
    const int bin   = blockIdx.x & 511;
    const int chunk = blockIdx.x >> 9;   // 0..7
    const int b  = bin & 7;              // batch fast -> XCD spread
    const int s  = bin >> 3;
    const int bs = b * SN + s;
    const int nq = cnt[bs];
    const int q0 = chunk * 64;
    if (q0 >= nq) return;                // block-uniform early out (pre-barrier)

    const int tid  = threadIdx.x;
    const int tx   = tid & 15;           // token-cols
    const int ty   = tid >> 4;           // pair-slots q0+ty*4..+3
    const int lane = tid & 63;
    const int g    = lane >> 4;          // 16-lane group within wave

    int pid[4];
    float swp[4];
    const float* Ab[4];
    #pragma unroll
    for (int i = 0; i < 4; ++i) {
        int e  = list[bs * 512 + min(q0 + ty * 4 + i, nq - 1)];  // clamp: dup pair
        int q  = e & 0xffff;
        int si = (e >> 16) & 7;
        pid[i] = ((b << 9) + q) * 8 + si;
        swp[i] = sel_w[pid[i]];
        Ab[i]  = qt + ((size_t)(b << 9) + q) * 128;
    }
    const float* kb = kT + ((size_t)bs << 14);

    __shared__ float ksh[64 * 128];      // 32 KB: one d-half of the k-block

    float acc[4][8];
    #pragma unroll
    for (int i = 0; i < 4; ++i)
        #pragma unroll
        for (int j = 0; j < 8; ++j) acc[i][j] = 0.f;

    for (int h = 0; h < 2; ++h) {
        const f4* src = (const f4*)(kb + (size_t)h * 64 * 128);
        __syncthreads();                 // protect prior-half reads
        #pragma unroll
        for (int it2 = 0; it2 < 8; ++it2)
            ((f4*)ksh)[it2 * 256 + tid] = src[it2 * 256 + tid];
        __syncthreads();

        #pragma unroll 2
        for (int k0 = 0; k0 < 64; k0 += 4) {
            f4 a[4];
            #pragma unroll
            for (int i = 0; i < 4; ++i)
                a[i] = *(const f4*)(Ab[i] + h * 64 + k0);  // 16-lane broadcast
            f4 wl[4], wh[4];
            #pragma unroll
            for (int kk = 0; kk < 4; ++kk) {
                wl[kk] = *(const f4*)&ksh[(k0 + kk) * 128 + tx * 4];
                wh[kk] = *(const f4*)&ksh[(k0 + kk) * 128 + 64 + tx * 4];
            }
            #pragma unroll
            for (int i = 0; i < 4; ++i)
                #pragma unroll
                for (int kk = 0; kk < 4; ++kk)
                    #pragma unroll
                    for (int j = 0; j < 4; ++j) {
                        acc[i][j]     = fmaf(a[i][kk], wl[kk][j], acc[i][j]);
                        acc[i][4 + j] = fmaf(a[i][kk], wh[kk][j], acc[i][4 + j]);
                    }
        }
    }

    // ---- exact in-register top-16 + softmax, 4 pids interleaved (R17) ----
    float s8[4][8];
    #pragma unroll
    for (int i = 0; i < 4; ++i)
        #pragma unroll
        for (int j = 0; j < 8; ++j) s8[i][j] = acc[i][j] * SCALE;

    float m0[4], myM[4];
    int   myT[4];
    #pragma unroll
    for (int i = 0; i < 4; ++i) { m0[i] = 0.f; myM[i] = 0.f; myT[i] = 0; }

    for (int it = 0; it < 16; ++it) {
        #pragma unroll
        for (int i = 0; i < 4; ++i) {
            // exact fp32 group max (tree + 4-step shfl, stays in 16-lane group)
            float v01 = fmaxf(s8[i][0], s8[i][1]);
            float v23 = fmaxf(s8[i][2], s8[i][3]);
            float v45 = fmaxf(s8[i][4], s8[i][5]);
            float v67 = fmaxf(s8[i][6], s8[i][7]);
            float m = fmaxf(fmaxf(v01, v23), fmaxf(v45, v67));
            #pragma unroll
            for (int off = 8; off > 0; off >>= 1) m = fmaxf(m, __shfl_xor(m, off));

            // per-lane lowest hit slot in each half (descending scan)
            int jlo = 4, jhi = 4;                     // 4 = no hit
            #pragma unroll
            for (int j = 3; j >= 0; --j) jlo = (s8[i][j]     == m) ? j : jlo;
            #pragma unroll
            for (int j = 3; j >= 0; --j) jhi = (s8[i][4 + j] == m) ? j : jhi;

            // exact lowest-t via ballots: lower half beats upper; lowest lane
            // = lowest t (lane tx owns t = 4tx..4tx+3 / 64+4tx..64+4tx+3)
            u64 blo = __ballot(jlo < 4);
            u64 bhi = __ballot(jhi < 4);
            unsigned mlo = (unsigned)((blo >> (g * 16)) & 0xFFFFu);
            unsigned mhi = (unsigned)((bhi >> (g * 16)) & 0xFFFFu);
            bool lo = (mlo != 0);
            unsigned msel = lo ? mlo : mhi;
            int L = __ffs(msel) - 1;                  // winner lane in group
            int jsel = lo ? jlo : jhi;
            int jwin = __shfl(jsel, g * 16 + L);      // winner's slot-in-half
            int tstar = (lo ? 0 : 64) + 4 * L + jwin;

            m0[i] = (it == 0) ? m : m0[i];
            bool rec = (tx == it);
            myT[i] = rec ? tstar : myT[i];
            myM[i] = rec ? m : myM[i];

            // branch-free knock of the unique winning slot
            int slot = (lo ? 0 : 4) + jwin;           // uniform within group
            bool winlane = (tx == L);
            #pragma unroll
            for (int j = 0; j < 8; ++j)
                s8[i][j] = (winlane && slot == j) ? NINF : s8[i][j];
        }
    }

    #pragma unroll
    for (int i = 0; i < 4; ++i) {
        float myE = expf(myM[i] - m0[i]);      // exact
        float Z = myE;
        #pragma unroll
        for (int off = 8; off > 0; off >>= 1) Z += __shfl_xor(Z, off);
        float cs = swp[i] / Z;                 // fold stat weight in

        pvt[(size_t)pid[i] * TOK_K + tx] = myT[i];   // dup pids: identical data
        pvw[(size_t)pid[i] * TOK_K + tx] = myE * cs;
    }
}

// ---------------------------------------------------------------------------
// K3 (fused): PV accumulate on RAW values + output projection with M_vo.
// One wave per (b,q): PV row in registers -> LDS (same-wave, in-order) ->
// row @ M_vo (L1-resident) -> direct store to d_out. No atomics.
// t clamped to [0,127]: stale pvt for unbinned pids is harmless (pvw==0).
// ---------------------------------------------------------------------------
__global__ __launch_bounds__(256) void tok_pv3(const float* __restrict__ values,
                                               const int* __restrict__ sel_i,
                                               const int* __restrict__ pvt,
                                               const float* __restrict__ pvw,
                                               const float* __restrict__ M_vo,
                                               float* __restrict__ out)
{
    const int wid  = threadIdx.x >> 6;
    const int bq   = blockIdx.x * 4 + wid;
    const int lane = threadIdx.x & 63;
    const int b    = bq >> 9;

    float o0 = 0.f, o1 = 0.f;
    #pragma unroll
    for (int si = 0; si < STAT_K; ++si) {
        const int pid = bq * STAT_K + si;
        const int s   = sel_i[pid];
        const float* vb = values + ((size_t)(b * SN + s) << 14);
        const int*   tp = pvt + (size_t)pid * TOK_K;
        const float* wp = pvw + (size_t)pid * TOK_K;
        #pragma unroll
        for (int j = 0; j < TOK_K; ++j) {
            int   t = tp[j] & 127;           // wave-uniform; clamp stale entries
            float w = wp[j];                 // ==0 for skipped pids: exact no-op
            f2 x = *(const f2*)(vb + (size_t)t * 128 + lane * 2);
            o0 = fmaf(w, x[0], o0);
            o1 = fmaf(w, x[1], o1);
        }
    }

    __shared__ float pre[4][128];
    *(f2*)&pre[wid][lane * 2] = (f2){o0, o1};
    __asm__ __volatile__("" ::: "memory");
    __builtin_amdgcn_wave_barrier();        // same-wave LDS RAW: in-order pipe
    __asm__ __volatile__("" ::: "memory");

    float r0 = 0.f, r1 = 0.f;
    #pragma unroll 4
    for (int d = 0; d < 128; ++d) {
        float p = pre[wid][d];               // broadcast read
        f2 w = *(const f2*)(M_vo + (size_t)d * 128 + lane * 2);
        r0 = fmaf(p, w[0], r0);
        r1 = fmaf(p, w[1], r1);
    }
    *(f2*)&out[(size_t)bq * 128 + lane * 2] = (f2){r0, r1};
}

// ---------------------------------------------------------------------------
extern "C" void kernel_launch(void* const* d_in, const int* in_sizes, int n_in,
                              void* d_out, int out_size, void* d_ws, size_t ws_size,
                              hipStream_t stream)
{
    const float* queries    = (const float*)d_in[0];
    const float* stat_keys  = (const float*)d_in[1];
    const float* token_keys = (const float*)d_in[2];
    const float* values     = (const float*)d_in[3];
    const int*   vlen       = (const int*)d_in[4];
    const float* Wq_stat    = (const float*)d_in[5];
    const float* Wq_token   = (const float*)d_in[6];
    const float* Wk_stat    = (const float*)d_in[7];
    const float* Wk_token   = (const float*)d_in[8];
    const float* Wv         = (const float*)d_in[9];
    const float* Wo         = (const float*)d_in[10];

    char* ws = (char*)d_ws;
    float* q_stat  = (float*)(ws);                 // 2 MB
    float* q_tok   = (float*)(ws + 2097152);       // 2 MB
    float* k_stat  = (float*)(ws + 4194304);       // 256 KB
    float* M_vo    = (float*)(ws + 4456448);       // 64 KB (Wv @ Wo)
    int*   sel_i   = (int*)  (ws + 4521984);       // 128 KB
    float* sel_w   = (float*)(ws + 4653056);       // 128 KB
    float* kT      = (float*)(ws + 4784128);       // 32 MB
    int*   pvt     = (int*)  (ws + 38338560);      // 2 MB
    float* pvw     = (float*)(ws + 40435712);      // 2 MB
    int*   list    = (int*)  (ws + 42532864);      // 1 MB
    int*   cnt     = (int*)  (ws + 43581440);      // 2 KB   (total ~43.6 MB)

    // Projections feeding selection (fp32 exact) + Wv@Wo fold + cnt zeroing
    proj_all<<<1163, 256, 0, stream>>>(queries, stat_keys, token_keys,
                                       Wq_stat, Wq_token, Wk_stat, Wk_token, Wv, Wo,
                                       q_stat, q_tok, k_stat, kT, M_vo, cnt);

    // Stat-level top-8 + weights + bin append + pvw zeroing (fused)
    stat_topk<<<BB * QN, 64, 0, stream>>>(q_stat, k_stat, vlen, sel_i, sel_w,
                                          cnt, list, pvw);

    // K1: token scores (k-block LDS-staged) + exact top-16 + weights
    tok_score_sel<<<4096, 256, 0, stream>>>(q_tok, kT, cnt, list, sel_w, pvt, pvw);

    // K3: PV + output projection fused, one wave per (b,q), direct to d_out
    tok_pv3<<<BB * QN / 4, 256, 0, stream>>>(values, sel_i, pvt, pvw, M_vo,
                                             (float*)d_out);
}

// Round 22
// 171.551 us; speedup vs baseline: 1.2571x; 1.0121x over previous
//
#include <hip/hip_runtime.h>
#include <hip/hip_bf16.h>
#include <math.h>

// Problem constants (from setup_inputs)
#define BB 8
#define QN 512
#define SN 64
#define TN 128
#define DD 128
#define STAT_K 8
#define TOK_K 16
#define SCALE 0.08838834764831845f   // 1/sqrt(128)
#define NEGBIG -1e6f
#define NINF  -3.4e38f

typedef float f4 __attribute__((ext_vector_type(4)));
typedef float f2 __attribute__((ext_vector_type(2)));
typedef unsigned long long u64;

// ---------------------------------------------------------------------------
// GEMM tile, 4 rows/thread, W staged in LDS in two 32 KB halves (R20/21-proven
// pattern): W-reads become broadcast ds_read_b128 (12-cyc, 2-way alias = free)
// instead of ~250-cyc L2 streams; A-loads (16-lane broadcast) ride under the
// 256-cyc FMA blocks. 32 KB LDS -> 4 blocks/CU.
// transposed: per-bin col-major store (see R11 notes).
// ---------------------------------------------------------------------------
__device__ __forceinline__ void proj_tile4_lds(const float* __restrict__ A,
                                               const float* __restrict__ W,
                                               float* __restrict__ C,
                                               int rowBase, int transposed,
                                               int tid, float* __restrict__ wsh)
{
    const int tx = tid & 15;    // cols tx*4..+3 and 64+tx*4..+3
    const int ty = tid >> 4;    // 0..15, rows ty*4..+3
    const float* Ab = A + (size_t)(rowBase + ty * 4) * 128;

    float acc[4][8];
    #pragma unroll
    for (int i = 0; i < 4; ++i)
        #pragma unroll
        for (int j = 0; j < 8; ++j) acc[i][j] = 0.f;

    for (int h = 0; h < 2; ++h) {
        // stage W half h: 64 k-rows x 128 cols = 2048 f4, 8 per thread
        const f4* src = (const f4*)(W + (size_t)h * 64 * 128);
        __syncthreads();                 // protect prior-half reads
        #pragma unroll
        for (int i2 = 0; i2 < 8; ++i2)
            ((f4*)wsh)[i2 * 256 + tid] = src[i2 * 256 + tid];
        __syncthreads();

        #pragma unroll 2
        for (int k0 = 0; k0 < 64; k0 += 4) {
            f4 a[4];
            #pragma unroll
            for (int i = 0; i < 4; ++i)
                a[i] = *(const f4*)(Ab + i * 128 + h * 64 + k0);  // 16-lane bcast
            f4 wl[4], wh[4];
            #pragma unroll
            for (int kk = 0; kk < 4; ++kk) {
                wl[kk] = *(const f4*)&wsh[(k0 + kk) * 128 + tx * 4];
                wh[kk] = *(const f4*)&wsh[(k0 + kk) * 128 + 64 + tx * 4];
            }
            #pragma unroll
            for (int i = 0; i < 4; ++i)
                #pragma unroll
                for (int kk = 0; kk < 4; ++kk)
                    #pragma unroll
                    for (int j = 0; j < 4; ++j) {
                        acc[i][j]     = fmaf(a[i][kk], wl[kk][j], acc[i][j]);
                        acc[i][4 + j] = fmaf(a[i][kk], wh[kk][j], acc[i][4 + j]);
                    }
        }
    }

    if (!transposed) {
        #pragma unroll
        for (int i = 0; i < 4; ++i) {
            size_t row = (size_t)rowBase + ty * 4 + i;
            f4 lo = {acc[i][0], acc[i][1], acc[i][2], acc[i][3]};
            f4 hi = {acc[i][4], acc[i][5], acc[i][6], acc[i][7]};
            *(f4*)&C[row * 128 + tx * 4]      = lo;
            *(f4*)&C[row * 128 + 64 + tx * 4] = hi;
        }
    } else {
        float* Cb = C + ((size_t)(rowBase >> 7) << 14);    // bin base
        const int rb = (rowBase & 127) + ty * 4;           // row within bin
        #pragma unroll
        for (int j = 0; j < 4; ++j) {
            int clo = tx * 4 + j;
            int chi = 64 + tx * 4 + j;
            f4 v0 = {acc[0][j], acc[1][j], acc[2][j], acc[3][j]};
            f4 v1 = {acc[0][4 + j], acc[1][4 + j], acc[2][4 + j], acc[3][4 + j]};
            *(f4*)&Cb[clo * 128 + rb] = v0;
            *(f4*)&Cb[chi * 128 + rb] = v1;
        }
    }
}

// Input projections + Wv@Wo fold + cnt zeroing, one launch, 64-row tiles.
__global__ __launch_bounds__(256) void proj_all(const float* __restrict__ queries,
                                                const float* __restrict__ stat_keys,
                                                const float* __restrict__ token_keys,
                                                const float* __restrict__ Wq_stat,
                                                const float* __restrict__ Wq_token,
                                                const float* __restrict__ Wk_stat,
                                                const float* __restrict__ Wk_token,
                                                const float* __restrict__ Wv,
                                                const float* __restrict__ Wo,
                                                float* __restrict__ q_stat,
                                                float* __restrict__ q_tok,
                                                float* __restrict__ k_stat,
                                                float* __restrict__ kT,
                                                float* __restrict__ M_vo,
                                                int* __restrict__ cnt)
{
    __shared__ float wsh[64 * 128];      // 32 KB: one k-half of W
    const int bi = blockIdx.x;
    if (bi < 1024)       proj_tile4_lds(token_keys, Wk_token, kT,     bi * 64,           1, threadIdx.x, wsh);
    else if (bi < 1088)  proj_tile4_lds(queries,    Wq_stat,  q_stat, (bi - 1024) * 64,  0, threadIdx.x, wsh);
    else if (bi < 1152)  proj_tile4_lds(queries,    Wq_token, q_tok,  (bi - 1088) * 64,  0, threadIdx.x, wsh);
    else if (bi < 1160)  proj_tile4_lds(stat_keys,  Wk_stat,  k_stat, (bi - 1152) * 64,  0, threadIdx.x, wsh);
    else if (bi < 1162)  proj_tile4_lds(Wv,         Wo,       M_vo,   (bi - 1160) * 64,  0, threadIdx.x, wsh);
    else {
        for (int i = threadIdx.x; i < BB * SN; i += 256) cnt[i] = 0;
    }
}

// ---------------------------------------------------------------------------
// Stat level + binning fused (R12-proven). Unbinned (wv==0) pids get their
// pvw row zeroed here (tok_pv3 clamps stale pvt tokens).
// ---------------------------------------------------------------------------
__global__ __launch_bounds__(64, 4) void stat_topk(const float* __restrict__ qs,
                                                   const float* __restrict__ ks,
                                                   const int* __restrict__ vlen,
                                                   int* __restrict__ sel_i,
                                                   float* __restrict__ sel_w,
                                                   int* __restrict__ cnt,
                                                   int* __restrict__ list,
                                                   float* __restrict__ pvw)
{
    const int bq   = blockIdx.x;
    const int b    = bq >> 9;
    const int lane = threadIdx.x;

    const f4* q4 = (const f4*)(qs + (size_t)bq * 128);
    const f4* k4 = (const f4*)(ks + (size_t)(b * SN + lane) * 128);
    float acc = 0.f;
    #pragma unroll 8
    for (int kk = 0; kk < 32; ++kk) {
        f4 q = q4[kk];
        f4 k = k4[kk];
        acc = fmaf(q[0], k[0], acc);
        acc = fmaf(q[1], k[1], acc);
        acc = fmaf(q[2], k[2], acc);
        acc = fmaf(q[3], k[3], acc);
    }
    float score = acc * SCALE;
    if (lane >= vlen[b]) score = NEGBIG;

    float work = score;
    float tv[STAT_K];
    int   ti[STAT_K];
    #pragma unroll
    for (int j = 0; j < STAT_K; ++j) {
        float m = work;
        #pragma unroll
        for (int off = 32; off > 0; off >>= 1) m = fmaxf(m, __shfl_xor(m, off));
        unsigned long long ball = __ballot(work == m);
        int L = __ffsll(ball) - 1;     // lowest index wins ties
        tv[j] = m;
        ti[j] = L;
        if (lane == L) work = NINF;
    }

    float w[STAT_K];
    float Z = 0.f;
    #pragma unroll
    for (int j = 0; j < STAT_K; ++j) { w[j] = expf(tv[j] - tv[0]); Z += w[j]; }
    float invZ = 1.f / Z;

    if (lane < STAT_K) {
        float wv = w[lane] * invZ;
        int pid = bq * STAT_K + lane;
        sel_i[pid] = ti[lane];
        sel_w[pid] = wv;
        if (wv != 0.f) {                         // sw==0: exactly-zero contribution
            int s  = ti[lane];
            int bs = b * SN + s;
            int pos = atomicAdd(&cnt[bs], 1);
            list[bs * 512 + pos] = (bq & 511) | (lane << 16);
        } else {
            #pragma unroll
            for (int j = 0; j < TOK_K; ++j)      // never written downstream: zero
                pvw[(size_t)pid * TOK_K + j] = 0.f;
        }
    }
}

// ---------------------------------------------------------------------------
// K1 (fused): token scores + EXACT top-16 + softmax weights. k-block staged
// in LDS in two 32 KB halves (R20/21-proven). NEW: 512-thread blocks (8
// waves) share one stage, chunk=128 pairs -> 2x working waves/SIMD and 2x
// staging amortization. Per-thread code unchanged (4 pids per 16-lane group,
// R17-proven exact selection).
// ---------------------------------------------------------------------------
__global__ __launch_bounds__(512) void tok_score_sel(const float* __restrict__ qt,
                                                     const float* __restrict__ kT,
                                                     const int* __restrict__ cnt,
                                                     const int* __restrict__ list,
                                                     const float* __restrict__ sel_w,
                                                     int* __restrict__ pvt,
                                                     float* __restrict__ pvw)
{
    const int bin   = blockIdx.x & 511;
    const int chunk = blockIdx.x >> 9;   // 0..3
    const int b  = bin & 7;              // batch fast -> XCD spread
    const int s  = bin >> 3;
    const int bs = b * SN + s;
    const int nq = cnt[bs];
    const int q0 = chunk * 128;
    if (q0 >= nq) return;                // block-uniform early out (pre-barrier)

    const int tid  = threadIdx.x;
    const int tx   = tid & 15;           // token-cols
    const int ty   = tid >> 4;           // 0..31, pair-slots q0+ty*4..+3
    const int lane = tid & 63;
    const int g    = lane >> 4;          // 16-lane group within wave

    int pid[4];
    float swp[4];
    const float* Ab[4];
    #pragma unroll
    for (int i = 0; i < 4; ++i) {
        int e  = list[bs * 512 + min(q0 + ty * 4 + i, nq - 1)];  // clamp: dup pair
        int q  = e & 0xffff;
        int si = (e >> 16) & 7;
        pid[i] = ((b << 9) + q) * 8 + si;
        swp[i] = sel_w[pid[i]];
        Ab[i]  = qt + ((size_t)(b << 9) + q) * 128;
    }
    const float* kb = kT + ((size_t)bs << 14);

    __shared__ float ksh[64 * 128];      // 32 KB: one d-half of the k-block

    float acc[4][8];
    #pragma unroll
    for (int i = 0; i < 4; ++i)
        #pragma unroll
        for (int j = 0; j < 8; ++j) acc[i][j] = 0.f;

    for (int h = 0; h < 2; ++h) {
        const f4* src = (const f4*)(kb + (size_t)h * 64 * 128);
        __syncthreads();                 // protect prior-half reads
        #pragma unroll
        for (int it2 = 0; it2 < 4; ++it2)
            ((f4*)ksh)[it2 * 512 + tid] = src[it2 * 512 + tid];
        __syncthreads();

        #pragma unroll 2
        for (int k0 = 0; k0 < 64; k0 += 4) {
            f4 a[4];
            #pragma unroll
            for (int i = 0; i < 4; ++i)
                a[i] = *(const f4*)(Ab[i] + h * 64 + k0);  // 16-lane broadcast
            f4 wl[4], wh[4];
            #pragma unroll
            for (int kk = 0; kk < 4; ++kk) {
                wl[kk] = *(const f4*)&ksh[(k0 + kk) * 128 + tx * 4];
                wh[kk] = *(const f4*)&ksh[(k0 + kk) * 128 + 64 + tx * 4];
            }
            #pragma unroll
            for (int i = 0; i < 4; ++i)
                #pragma unroll
                for (int kk = 0; kk < 4; ++kk)
                    #pragma unroll
                    for (int j = 0; j < 4; ++j) {
                        acc[i][j]     = fmaf(a[i][kk], wl[kk][j], acc[i][j]);
                        acc[i][4 + j] = fmaf(a[i][kk], wh[kk][j], acc[i][4 + j]);
                    }
        }
    }

    // ---- exact in-register top-16 + softmax, 4 pids interleaved (R17) ----
    float s8[4][8];
    #pragma unroll
    for (int i = 0; i < 4; ++i)
        #pragma unroll
        for (int j = 0; j < 8; ++j) s8[i][j] = acc[i][j] * SCALE;

    float m0[4], myM[4];
    int   myT[4];
    #pragma unroll
    for (int i = 0; i < 4; ++i) { m0[i] = 0.f; myM[i] = 0.f; myT[i] = 0; }

    for (int it = 0; it < 16; ++it) {
        #pragma unroll
        for (int i = 0; i < 4; ++i) {
            // exact fp32 group max (tree + 4-step shfl, stays in 16-lane group)
            float v01 = fmaxf(s8[i][0], s8[i][1]);
            float v23 = fmaxf(s8[i][2], s8[i][3]);
            float v45 = fmaxf(s8[i][4], s8[i][5]);
            float v67 = fmaxf(s8[i][6], s8[i][7]);
            float m = fmaxf(fmaxf(v01, v23), fmaxf(v45, v67));
            #pragma unroll
            for (int off = 8; off > 0; off >>= 1) m = fmaxf(m, __shfl_xor(m, off));

            // per-lane lowest hit slot in each half (descending scan)
            int jlo = 4, jhi = 4;                     // 4 = no hit
            #pragma unroll
            for (int j = 3; j >= 0; --j) jlo = (s8[i][j]     == m) ? j : jlo;
            #pragma unroll
            for (int j = 3; j >= 0; --j) jhi = (s8[i][4 + j] == m) ? j : jhi;

            // exact lowest-t via ballots: lower half beats upper; lowest lane
            // = lowest t (lane tx owns t = 4tx..4tx+3 / 64+4tx..64+4tx+3)
            u64 blo = __ballot(jlo < 4);
            u64 bhi = __ballot(jhi < 4);
            unsigned mlo = (unsigned)((blo >> (g * 16)) & 0xFFFFu);
            unsigned mhi = (unsigned)((bhi >> (g * 16)) & 0xFFFFu);
            bool lo = (mlo != 0);
            unsigned msel = lo ? mlo : mhi;
            int L = __ffs(msel) - 1;                  // winner lane in group
            int jsel = lo ? jlo : jhi;
            int jwin = __shfl(jsel, g * 16 + L);      // winner's slot-in-half
            int tstar = (lo ? 0 : 64) + 4 * L + jwin;

            m0[i] = (it == 0) ? m : m0[i];
            bool rec = (tx == it);
            myT[i] = rec ? tstar : myT[i];
            myM[i] = rec ? m : myM[i];

            // branch-free knock of the unique winning slot
            int slot = (lo ? 0 : 4) + jwin;           // uniform within group
            bool winlane = (tx == L);
            #pragma unroll
            for (int j = 0; j < 8; ++j)
                s8[i][j] = (winlane && slot == j) ? NINF : s8[i][j];
        }
    }

    #pragma unroll
    for (int i = 0; i < 4; ++i) {
        float myE = expf(myM[i] - m0[i]);      // exact
        float Z = myE;
        #pragma unroll
        for (int off = 8; off > 0; off >>= 1) Z += __shfl_xor(Z, off);
        float cs = swp[i] / Z;                 // fold stat weight in

        pvt[(size_t)pid[i] * TOK_K + tx] = myT[i];   // dup pids: identical data
        pvw[(size_t)pid[i] * TOK_K + tx] = myE * cs;
    }
}

// ---------------------------------------------------------------------------
// K3 (fused): PV accumulate on RAW values + output projection with M_vo.
// One wave per (b,q): PV row in registers -> LDS (same-wave, in-order) ->
// row @ M_vo (L1-resident) -> direct store to d_out. No atomics.
// t clamped to [0,127]: stale pvt for unbinned pids is harmless (pvw==0).
// ---------------------------------------------------------------------------
__global__ __launch_bounds__(256) void tok_pv3(const float* __restrict__ values,
                                               const int* __restrict__ sel_i,
                                               const int* __restrict__ pvt,
                                               const float* __restrict__ pvw,
                                               const float* __restrict__ M_vo,
                                               float* __restrict__ out)
{
    const int wid  = threadIdx.x >> 6;
    const int bq   = blockIdx.x * 4 + wid;
    const int lane = threadIdx.x & 63;
    const int b    = bq >> 9;

    float o0 = 0.f, o1 = 0.f;
    #pragma unroll
    for (int si = 0; si < STAT_K; ++si) {
        const int pid = bq * STAT_K + si;
        const int s   = sel_i[pid];
        const float* vb = values + ((size_t)(b * SN + s) << 14);
        const int*   tp = pvt + (size_t)pid * TOK_K;
        const float* wp = pvw + (size_t)pid * TOK_K;
        #pragma unroll
        for (int j = 0; j < TOK_K; ++j) {
            int   t = tp[j] & 127;           // wave-uniform; clamp stale entries
            float w = wp[j];                 // ==0 for skipped pids: exact no-op
            f2 x = *(const f2*)(vb + (size_t)t * 128 + lane * 2);
            o0 = fmaf(w, x[0], o0);
            o1 = fmaf(w, x[1], o1);
        }
    }

    __shared__ float pre[4][128];
    *(f2*)&pre[wid][lane * 2] = (f2){o0, o1};
    __asm__ __volatile__("" ::: "memory");
    __builtin_amdgcn_wave_barrier();        // same-wave LDS RAW: in-order pipe
    __asm__ __volatile__("" ::: "memory");

    float r0 = 0.f, r1 = 0.f;
    #pragma unroll 4
    for (int d = 0; d < 128; ++d) {
        float p = pre[wid][d];               // broadcast read
        f2 w = *(const f2*)(M_vo + (size_t)d * 128 + lane * 2);
        r0 = fmaf(p, w[0], r0);
        r1 = fmaf(p, w[1], r1);
    }
    *(f2*)&out[(size_t)bq * 128 + lane * 2] = (f2){r0, r1};
}

// ---------------------------------------------------------------------------
extern "C" void kernel_launch(void* const* d_in, const int* in_sizes, int n_in,
                              void* d_out, int out_size, void* d_ws, size_t ws_size,
                              hipStream_t stream)
{
    const float* queries    = (const float*)d_in[0];
    const float* stat_keys  = (const float*)d_in[1];
    const float* token_keys = (const float*)d_in[2];
    const float* values     = (const float*)d_in[3];
    const int*   vlen       = (const int*)d_in[4];
    const float* Wq_stat    = (const float*)d_in[5];
    const float* Wq_token   = (const float*)d_in[6];
    const float* Wk_stat    = (const float*)d_in[7];
    const float* Wk_token   = (const float*)d_in[8];
    const float* Wv         = (const float*)d_in[9];
    const float* Wo         = (const float*)d_in[10];

    char* ws = (char*)d_ws;
    float* q_stat  = (float*)(ws);                 // 2 MB
    float* q_tok   = (float*)(ws + 2097152);       // 2 MB
    float* k_stat  = (float*)(ws + 4194304);       // 256 KB
    float* M_vo    = (float*)(ws + 4456448);       // 64 KB (Wv @ Wo)
    int*   sel_i   = (int*)  (ws + 4521984);       // 128 KB
    float* sel_w   = (float*)(ws + 4653056);       // 128 KB
    float* kT      = (float*)(ws + 4784128);       // 32 MB
    int*   pvt     = (int*)  (ws + 38338560);      // 2 MB
    float* pvw     = (float*)(ws + 40435712);      // 2 MB
    int*   list    = (int*)  (ws + 42532864);      // 1 MB
    int*   cnt     = (int*)  (ws + 43581440);      // 2 KB   (total ~43.6 MB)

    // Projections feeding selection (fp32 exact) + Wv@Wo fold + cnt zeroing
    proj_all<<<1163, 256, 0, stream>>>(queries, stat_keys, token_keys,
                                       Wq_stat, Wq_token, Wk_stat, Wk_token, Wv, Wo,
                                       q_stat, q_tok, k_stat, kT, M_vo, cnt);

    // Stat-level top-8 + weights + bin append + pvw zeroing (fused)
    stat_topk<<<BB * QN, 64, 0, stream>>>(q_stat, k_stat, vlen, sel_i, sel_w,
                                          cnt, list, pvw);

    // K1: token scores (k-block LDS-staged, 8-wave blocks, chunk=128)
    tok_score_sel<<<2048, 512, 0, stream>>>(q_tok, kT, cnt, list, sel_w, pvt, pvw);

    // K3: PV + output projection fused, one wave per (b,q), direct to d_out
    tok_pv3<<<BB * QN / 4, 256, 0, stream>>>(values, sel_i, pvt, pvw, M_vo,
                                             (float*)d_out);
}

// Round 23
// 159.632 us; speedup vs baseline: 1.3509x; 1.0747x over previous
//
#include <hip/hip_runtime.h>
#include <hip/hip_bf16.h>
#include <math.h>

// Problem constants (from setup_inputs)
#define BB 8
#define QN 512
#define SN 64
#define TN 128
#define DD 128
#define STAT_K 8
#define TOK_K 16
#define SCALE 0.08838834764831845f   // 1/sqrt(128)
#define NEGBIG -1e6f
#define NINF  -3.4e38f

typedef float f4 __attribute__((ext_vector_type(4)));
typedef float f2 __attribute__((ext_vector_type(2)));
typedef unsigned long long u64;

// ---------------------------------------------------------------------------
// GEMM tile, 4 rows/thread, W staged in LDS in two 32 KB halves (R20/21-proven
// pattern): W-reads become broadcast ds_read_b128 (12-cyc, 2-way alias = free)
// instead of ~250-cyc L2 streams; A-loads (16-lane broadcast) ride under the
// 256-cyc FMA blocks. 32 KB LDS -> 4 blocks/CU.
// ---------------------------------------------------------------------------
__device__ __forceinline__ void proj_tile4_lds(const float* __restrict__ A,
                                               const float* __restrict__ W,
                                               float* __restrict__ C,
                                               int rowBase, int tid,
                                               float* __restrict__ wsh)
{
    const int tx = tid & 15;    // cols tx*4..+3 and 64+tx*4..+3
    const int ty = tid >> 4;    // 0..15, rows ty*4..+3
    const float* Ab = A + (size_t)(rowBase + ty * 4) * 128;

    float acc[4][8];
    #pragma unroll
    for (int i = 0; i < 4; ++i)
        #pragma unroll
        for (int j = 0; j < 8; ++j) acc[i][j] = 0.f;

    for (int h = 0; h < 2; ++h) {
        // stage W half h: 64 k-rows x 128 cols = 2048 f4, 8 per thread
        const f4* src = (const f4*)(W + (size_t)h * 64 * 128);
        __syncthreads();                 // protect prior-half reads
        #pragma unroll
        for (int i2 = 0; i2 < 8; ++i2)
            ((f4*)wsh)[i2 * 256 + tid] = src[i2 * 256 + tid];
        __syncthreads();

        #pragma unroll 2
        for (int k0 = 0; k0 < 64; k0 += 4) {
            f4 a[4];
            #pragma unroll
            for (int i = 0; i < 4; ++i)
                a[i] = *(const f4*)(Ab + i * 128 + h * 64 + k0);  // 16-lane bcast
            f4 wl[4], wh[4];
            #pragma unroll
            for (int kk = 0; kk < 4; ++kk) {
                wl[kk] = *(const f4*)&wsh[(k0 + kk) * 128 + tx * 4];
                wh[kk] = *(const f4*)&wsh[(k0 + kk) * 128 + 64 + tx * 4];
            }
            #pragma unroll
            for (int i = 0; i < 4; ++i)
                #pragma unroll
                for (int kk = 0; kk < 4; ++kk)
                    #pragma unroll
                    for (int j = 0; j < 4; ++j) {
                        acc[i][j]     = fmaf(a[i][kk], wl[kk][j], acc[i][j]);
                        acc[i][4 + j] = fmaf(a[i][kk], wh[kk][j], acc[i][4 + j]);
                    }
        }
    }

    #pragma unroll
    for (int i = 0; i < 4; ++i) {
        size_t row = (size_t)rowBase + ty * 4 + i;
        f4 lo = {acc[i][0], acc[i][1], acc[i][2], acc[i][3]};
        f4 hi = {acc[i][4], acc[i][5], acc[i][6], acc[i][7]};
        *(f4*)&C[row * 128 + tx * 4]      = lo;
        *(f4*)&C[row * 128 + 64 + tx * 4] = hi;
    }
}

// Projections feeding selection + Wv@Wo fold + Wk_token transpose + cnt zero.
// kT projection is GONE (algebraic fold): token scores use q2 = q_tok @ Wk^T
// against RAW token_keys. 140 blocks.
__global__ __launch_bounds__(256) void proj_all(const float* __restrict__ queries,
                                                const float* __restrict__ stat_keys,
                                                const float* __restrict__ Wq_stat,
                                                const float* __restrict__ Wq_token,
                                                const float* __restrict__ Wk_stat,
                                                const float* __restrict__ Wk_token,
                                                const float* __restrict__ Wv,
                                                const float* __restrict__ Wo,
                                                float* __restrict__ q_stat,
                                                float* __restrict__ q_tok,
                                                float* __restrict__ k_stat,
                                                float* __restrict__ M_vo,
                                                float* __restrict__ WkT,
                                                int* __restrict__ cnt)
{
    __shared__ float wsh[64 * 128];      // 32 KB: one k-half of W
    const int bi = blockIdx.x;
    if (bi < 64)         proj_tile4_lds(queries,   Wq_stat,  q_stat, bi * 64,        threadIdx.x, wsh);
    else if (bi < 128)   proj_tile4_lds(queries,   Wq_token, q_tok, (bi - 64) * 64,  threadIdx.x, wsh);
    else if (bi < 136)   proj_tile4_lds(stat_keys, Wk_stat,  k_stat,(bi - 128) * 64, threadIdx.x, wsh);
    else if (bi < 138)   proj_tile4_lds(Wv,        Wo,       M_vo,  (bi - 136) * 64, threadIdx.x, wsh);
    else if (bi == 138) {
        // WkT[d][e] = Wk_token[e][d]
        #pragma unroll
        for (int i2 = 0; i2 < 16; ++i2) {
            int idx = i2 * 256 + threadIdx.x;    // f4 index 0..4095
            int e  = idx >> 5;
            int d4 = idx & 31;
            f4 v = *(const f4*)(Wk_token + (size_t)e * 128 + d4 * 4);
            WkT[(size_t)(d4 * 4 + 0) * 128 + e] = v[0];
            WkT[(size_t)(d4 * 4 + 1) * 128 + e] = v[1];
            WkT[(size_t)(d4 * 4 + 2) * 128 + e] = v[2];
            WkT[(size_t)(d4 * 4 + 3) * 128 + e] = v[3];
        }
    } else {
        for (int i = threadIdx.x; i < BB * SN; i += 256) cnt[i] = 0;
    }
}

// q2 = q_tok @ WkT (needs proj_all done -> separate launch). 64 blocks.
__global__ __launch_bounds__(256) void proj_q2(const float* __restrict__ q_tok,
                                               const float* __restrict__ WkT,
                                               float* __restrict__ q2)
{
    __shared__ float wsh[64 * 128];
    proj_tile4_lds(q_tok, WkT, q2, blockIdx.x * 64, threadIdx.x, wsh);
}

// ---------------------------------------------------------------------------
// Stat level + binning fused (R12-proven). Unbinned (wv==0) pids get their
// pvw row zeroed here (tok_pv3 clamps stale pvt tokens).
// ---------------------------------------------------------------------------
__global__ __launch_bounds__(64, 4) void stat_topk(const float* __restrict__ qs,
                                                   const float* __restrict__ ks,
                                                   const int* __restrict__ vlen,
                                                   int* __restrict__ sel_i,
                                                   float* __restrict__ sel_w,
                                                   int* __restrict__ cnt,
                                                   int* __restrict__ list,
                                                   float* __restrict__ pvw)
{
    const int bq   = blockIdx.x;
    const int b    = bq >> 9;
    const int lane = threadIdx.x;

    const f4* q4 = (const f4*)(qs + (size_t)bq * 128);
    const f4* k4 = (const f4*)(ks + (size_t)(b * SN + lane) * 128);
    float acc = 0.f;
    #pragma unroll 8
    for (int kk = 0; kk < 32; ++kk) {
        f4 q = q4[kk];
        f4 k = k4[kk];
        acc = fmaf(q[0], k[0], acc);
        acc = fmaf(q[1], k[1], acc);
        acc = fmaf(q[2], k[2], acc);
        acc = fmaf(q[3], k[3], acc);
    }
    float score = acc * SCALE;
    if (lane >= vlen[b]) score = NEGBIG;

    float work = score;
    float tv[STAT_K];
    int   ti[STAT_K];
    #pragma unroll
    for (int j = 0; j < STAT_K; ++j) {
        float m = work;
        #pragma unroll
        for (int off = 32; off > 0; off >>= 1) m = fmaxf(m, __shfl_xor(m, off));
        unsigned long long ball = __ballot(work == m);
        int L = __ffsll(ball) - 1;     // lowest index wins ties
        tv[j] = m;
        ti[j] = L;
        if (lane == L) work = NINF;
    }

    float w[STAT_K];
    float Z = 0.f;
    #pragma unroll
    for (int j = 0; j < STAT_K; ++j) { w[j] = expf(tv[j] - tv[0]); Z += w[j]; }
    float invZ = 1.f / Z;

    if (lane < STAT_K) {
        float wv = w[lane] * invZ;
        int pid = bq * STAT_K + lane;
        sel_i[pid] = ti[lane];
        sel_w[pid] = wv;
        if (wv != 0.f) {                         // sw==0: exactly-zero contribution
            int s  = ti[lane];
            int bs = b * SN + s;
            int pos = atomicAdd(&cnt[bs], 1);
            list[bs * 512 + pos] = (bq & 511) | (lane << 16);
        } else {
            #pragma unroll
            for (int j = 0; j < TOK_K; ++j)      // never written downstream: zero
                pvw[(size_t)pid * TOK_K + j] = 0.f;
        }
    }
}

// ---------------------------------------------------------------------------
// K1 (fused): token scores + EXACT top-16 + softmax weights. Scores computed
// against RAW token_keys via q2 (kT projection algebraically folded away).
// Staging transposes token_keys[t][d] -> ksh[d][t]: scalar ds_writes with
// t varying per lane (2-way banks = free); 8-wave blocks, chunk=128 (R22).
// Selection: R17-proven exact path, byte-identical.
// ---------------------------------------------------------------------------
__global__ __launch_bounds__(512) void tok_score_sel(const float* __restrict__ q2,
                                                     const float* __restrict__ token_keys,
                                                     const int* __restrict__ cnt,
                                                     const int* __restrict__ list,
                                                     const float* __restrict__ sel_w,
                                                     int* __restrict__ pvt,
                                                     float* __restrict__ pvw)
{
    const int bin   = blockIdx.x & 511;
    const int chunk = blockIdx.x >> 9;   // 0..3
    const int b  = bin & 7;              // batch fast -> XCD spread
    const int s  = bin >> 3;
    const int bs = b * SN + s;
    const int nq = cnt[bs];
    const int q0 = chunk * 128;
    if (q0 >= nq) return;                // block-uniform early out (pre-barrier)

    const int tid  = threadIdx.x;
    const int tx   = tid & 15;           // token-cols
    const int ty   = tid >> 4;           // 0..31, pair-slots q0+ty*4..+3
    const int lane = tid & 63;
    const int g    = lane >> 4;          // 16-lane group within wave

    int pid[4];
    float swp[4];
    const float* Ab[4];
    #pragma unroll
    for (int i = 0; i < 4; ++i) {
        int e  = list[bs * 512 + min(q0 + ty * 4 + i, nq - 1)];  // clamp: dup pair
        int q  = e & 0xffff;
        int si = (e >> 16) & 7;
        pid[i] = ((b << 9) + q) * 8 + si;
        swp[i] = sel_w[pid[i]];
        Ab[i]  = q2 + ((size_t)(b << 9) + q) * 128;
    }
    const float* kb = token_keys + ((size_t)bs << 14);   // raw [t][d] block

    __shared__ float ksh[64 * 128];      // 32 KB: one e-half, transposed [e][t]

    float acc[4][8];
    #pragma unroll
    for (int i = 0; i < 4; ++i)
        #pragma unroll
        for (int j = 0; j < 8; ++j) acc[i][j] = 0.f;

    const int st   = tid & 127;          // staging token
    const int dgrp = tid >> 7;           // 0..3 (wave-uniform)

    for (int h = 0; h < 2; ++h) {
        __syncthreads();                 // protect prior-half reads
        {
            const float* src = kb + (size_t)st * 128 + h * 64 + dgrp * 16;
            #pragma unroll
            for (int it2 = 0; it2 < 4; ++it2) {
                f4 v = *(const f4*)(src + it2 * 4);
                int dc = dgrp * 16 + it2 * 4;
                ksh[(dc + 0) * 128 + st] = v[0];   // banks: t%32, 2-way = free
                ksh[(dc + 1) * 128 + st] = v[1];
                ksh[(dc + 2) * 128 + st] = v[2];
                ksh[(dc + 3) * 128 + st] = v[3];
            }
        }
        __syncthreads();

        #pragma unroll 2
        for (int k0 = 0; k0 < 64; k0 += 4) {
            f4 a[4];
            #pragma unroll
            for (int i = 0; i < 4; ++i)
                a[i] = *(const f4*)(Ab[i] + h * 64 + k0);  // 16-lane broadcast
            f4 wl[4], wh[4];
            #pragma unroll
            for (int kk = 0; kk < 4; ++kk) {
                wl[kk] = *(const f4*)&ksh[(k0 + kk) * 128 + tx * 4];
                wh[kk] = *(const f4*)&ksh[(k0 + kk) * 128 + 64 + tx * 4];
            }
            #pragma unroll
            for (int i = 0; i < 4; ++i)
                #pragma unroll
                for (int kk = 0; kk < 4; ++kk)
                    #pragma unroll
                    for (int j = 0; j < 4; ++j) {
                        acc[i][j]     = fmaf(a[i][kk], wl[kk][j], acc[i][j]);
                        acc[i][4 + j] = fmaf(a[i][kk], wh[kk][j], acc[i][4 + j]);
                    }
        }
    }

    // ---- exact in-register top-16 + softmax, 4 pids interleaved (R17) ----
    float s8[4][8];
    #pragma unroll
    for (int i = 0; i < 4; ++i)
        #pragma unroll
        for (int j = 0; j < 8; ++j) s8[i][j] = acc[i][j] * SCALE;

    float m0[4], myM[4];
    int   myT[4];
    #pragma unroll
    for (int i = 0; i < 4; ++i) { m0[i] = 0.f; myM[i] = 0.f; myT[i] = 0; }

    for (int it = 0; it < 16; ++it) {
        #pragma unroll
        for (int i = 0; i < 4; ++i) {
            // exact fp32 group max (tree + 4-step shfl, stays in 16-lane group)
            float v01 = fmaxf(s8[i][0], s8[i][1]);
            float v23 = fmaxf(s8[i][2], s8[i][3]);
            float v45 = fmaxf(s8[i][4], s8[i][5]);
            float v67 = fmaxf(s8[i][6], s8[i][7]);
            float m = fmaxf(fmaxf(v01, v23), fmaxf(v45, v67));
            #pragma unroll
            for (int off = 8; off > 0; off >>= 1) m = fmaxf(m, __shfl_xor(m, off));

            // per-lane lowest hit slot in each half (descending scan)
            int jlo = 4, jhi = 4;                     // 4 = no hit
            #pragma unroll
            for (int j = 3; j >= 0; --j) jlo = (s8[i][j]     == m) ? j : jlo;
            #pragma unroll
            for (int j = 3; j >= 0; --j) jhi = (s8[i][4 + j] == m) ? j : jhi;

            // exact lowest-t via ballots: lower half beats upper; lowest lane
            // = lowest t (lane tx owns t = 4tx..4tx+3 / 64+4tx..64+4tx+3)
            u64 blo = __ballot(jlo < 4);
            u64 bhi = __ballot(jhi < 4);
            unsigned mlo = (unsigned)((blo >> (g * 16)) & 0xFFFFu);
            unsigned mhi = (unsigned)((bhi >> (g * 16)) & 0xFFFFu);
            bool lo = (mlo != 0);
            unsigned msel = lo ? mlo : mhi;
            int L = __ffs(msel) - 1;                  // winner lane in group
            int jsel = lo ? jlo : jhi;
            int jwin = __shfl(jsel, g * 16 + L);      // winner's slot-in-half
            int tstar = (lo ? 0 : 64) + 4 * L + jwin;

            m0[i] = (it == 0) ? m : m0[i];
            bool rec = (tx == it);
            myT[i] = rec ? tstar : myT[i];
            myM[i] = rec ? m : myM[i];

            // branch-free knock of the unique winning slot
            int slot = (lo ? 0 : 4) + jwin;           // uniform within group
            bool winlane = (tx == L);
            #pragma unroll
            for (int j = 0; j < 8; ++j)
                s8[i][j] = (winlane && slot == j) ? NINF : s8[i][j];
        }
    }

    #pragma unroll
    for (int i = 0; i < 4; ++i) {
        float myE = expf(myM[i] - m0[i]);      // exact
        float Z = myE;
        #pragma unroll
        for (int off = 8; off > 0; off >>= 1) Z += __shfl_xor(Z, off);
        float cs = swp[i] / Z;                 // fold stat weight in

        pvt[(size_t)pid[i] * TOK_K + tx] = myT[i];   // dup pids: identical data
        pvw[(size_t)pid[i] * TOK_K + tx] = myE * cs;
    }
}

// ---------------------------------------------------------------------------
// K3 (fused): PV accumulate on RAW values + output projection with M_vo.
// One wave per (b,q): PV row in registers -> LDS (same-wave, in-order) ->
// row @ M_vo (L1-resident) -> direct store to d_out. No atomics.
// t clamped to [0,127]: stale pvt for unbinned pids is harmless (pvw==0).
// ---------------------------------------------------------------------------
__global__ __launch_bounds__(256) void tok_pv3(const float* __restrict__ values,
                                               const int* __restrict__ sel_i,
                                               const int* __restrict__ pvt,
                                               const float* __restrict__ pvw,
                                               const float* __restrict__ M_vo,
                                               float* __restrict__ out)
{
    const int wid  = threadIdx.x >> 6;
    const int bq   = blockIdx.x * 4 + wid;
    const int lane = threadIdx.x & 63;
    const int b    = bq >> 9;

    float o0 = 0.f, o1 = 0.f;
    #pragma unroll
    for (int si = 0; si < STAT_K; ++si) {
        const int pid = bq * STAT_K + si;
        const int s   = sel_i[pid];
        const float* vb = values + ((size_t)(b * SN + s) << 14);
        const int*   tp = pvt + (size_t)pid * TOK_K;
        const float* wp = pvw + (size_t)pid * TOK_K;
        #pragma unroll
        for (int j = 0; j < TOK_K; ++j) {
            int   t = tp[j] & 127;           // wave-uniform; clamp stale entries
            float w = wp[j];                 // ==0 for skipped pids: exact no-op
            f2 x = *(const f2*)(vb + (size_t)t * 128 + lane * 2);
            o0 = fmaf(w, x[0], o0);
            o1 = fmaf(w, x[1], o1);
        }
    }

    __shared__ float pre[4][128];
    *(f2*)&pre[wid][lane * 2] = (f2){o0, o1};
    __asm__ __volatile__("" ::: "memory");
    __builtin_amdgcn_wave_barrier();        // same-wave LDS RAW: in-order pipe
    __asm__ __volatile__("" ::: "memory");

    float r0 = 0.f, r1 = 0.f;
    #pragma unroll 4
    for (int d = 0; d < 128; ++d) {
        float p = pre[wid][d];               // broadcast read
        f2 w = *(const f2*)(M_vo + (size_t)d * 128 + lane * 2);
        r0 = fmaf(p, w[0], r0);
        r1 = fmaf(p, w[1], r1);
    }
    *(f2*)&out[(size_t)bq * 128 + lane * 2] = (f2){r0, r1};
}

// ---------------------------------------------------------------------------
extern "C" void kernel_launch(void* const* d_in, const int* in_sizes, int n_in,
                              void* d_out, int out_size, void* d_ws, size_t ws_size,
                              hipStream_t stream)
{
    const float* queries    = (const float*)d_in[0];
    const float* stat_keys  = (const float*)d_in[1];
    const float* token_keys = (const float*)d_in[2];
    const float* values     = (const float*)d_in[3];
    const int*   vlen       = (const int*)d_in[4];
    const float* Wq_stat    = (const float*)d_in[5];
    const float* Wq_token   = (const float*)d_in[6];
    const float* Wk_stat    = (const float*)d_in[7];
    const float* Wk_token   = (const float*)d_in[8];
    const float* Wv         = (const float*)d_in[9];
    const float* Wo         = (const float*)d_in[10];

    char* ws = (char*)d_ws;
    float* q_stat  = (float*)(ws);                 // 2 MB
    float* q_tok   = (float*)(ws + 2097152);       // 2 MB
    float* k_stat  = (float*)(ws + 4194304);       // 256 KB
    float* M_vo    = (float*)(ws + 4456448);       // 64 KB (Wv @ Wo)
    float* WkT     = (float*)(ws + 4521984);       // 64 KB (Wk_token^T)
    int*   sel_i   = (int*)  (ws + 4587520);       // 128 KB
    float* sel_w   = (float*)(ws + 4718592);       // 128 KB
    float* q2      = (float*)(ws + 4849664);       // 2 MB (q_tok @ Wk^T)
    int*   pvt     = (int*)  (ws + 6946816);       // 2 MB
    float* pvw     = (float*)(ws + 9043968);       // 2 MB
    int*   list    = (int*)  (ws + 11141120);      // 1 MB
    int*   cnt     = (int*)  (ws + 12189696);      // 2 KB   (total ~12.2 MB)

    // Projections feeding selection + M_vo fold + Wk^T + cnt zeroing
    proj_all<<<140, 256, 0, stream>>>(queries, stat_keys,
                                      Wq_stat, Wq_token, Wk_stat, Wk_token, Wv, Wo,
                                      q_stat, q_tok, k_stat, M_vo, WkT, cnt);

    // q2 = q_tok @ Wk^T (token-score fold; needs proj_all outputs)
    proj_q2<<<64, 256, 0, stream>>>(q_tok, WkT, q2);

    // Stat-level top-8 + weights + bin append + pvw zeroing (fused)
    stat_topk<<<BB * QN, 64, 0, stream>>>(q_stat, k_stat, vlen, sel_i, sel_w,
                                          cnt, list, pvw);

    // K1: token scores vs RAW token_keys (LDS transpose-staged, 8-wave blocks)
    tok_score_sel<<<2048, 512, 0, stream>>>(q2, token_keys, cnt, list, sel_w,
                                            pvt, pvw);

    // K3: PV + output projection fused, one wave per (b,q), direct to d_out
    tok_pv3<<<BB * QN / 4, 256, 0, stream>>>(values, sel_i, pvt, pvw, M_vo,
                                             (float*)d_out);
}

// Round 24
// 158.571 us; speedup vs baseline: 1.3600x; 1.0067x over previous
//
#include <hip/hip_runtime.h>
#include <hip/hip_bf16.h>
#include <math.h>

// Problem constants (from setup_inputs)
#define BB 8
#define QN 512
#define SN 64
#define TN 128
#define DD 128
#define STAT_K 8
#define TOK_K 16
#define SCALE 0.08838834764831845f   // 1/sqrt(128)
#define NEGBIG -1e6f
#define NINF  -3.4e38f

typedef float f4 __attribute__((ext_vector_type(4)));
typedef float f2 __attribute__((ext_vector_type(2)));
typedef unsigned long long u64;

// ---------------------------------------------------------------------------
// GEMM tile, 4 rows/thread, W staged in LDS in two 32 KB halves (R20/21-proven
// pattern): W-reads become broadcast ds_read_b128 (12-cyc, 2-way alias = free)
// instead of ~250-cyc L2 streams; A-loads (16-lane broadcast) ride under the
// 256-cyc FMA blocks. 32 KB LDS -> 4 blocks/CU.
// ---------------------------------------------------------------------------
__device__ __forceinline__ void proj_tile4_lds(const float* __restrict__ A,
                                               const float* __restrict__ W,
                                               float* __restrict__ C,
                                               int rowBase, int tid,
                                               float* __restrict__ wsh)
{
    const int tx = tid & 15;    // cols tx*4..+3 and 64+tx*4..+3
    const int ty = tid >> 4;    // 0..15, rows ty*4..+3
    const float* Ab = A + (size_t)(rowBase + ty * 4) * 128;

    float acc[4][8];
    #pragma unroll
    for (int i = 0; i < 4; ++i)
        #pragma unroll
        for (int j = 0; j < 8; ++j) acc[i][j] = 0.f;

    for (int h = 0; h < 2; ++h) {
        // stage W half h: 64 k-rows x 128 cols = 2048 f4, 8 per thread
        const f4* src = (const f4*)(W + (size_t)h * 64 * 128);
        __syncthreads();                 // protect prior-half reads
        #pragma unroll
        for (int i2 = 0; i2 < 8; ++i2)
            ((f4*)wsh)[i2 * 256 + tid] = src[i2 * 256 + tid];
        __syncthreads();

        #pragma unroll 2
        for (int k0 = 0; k0 < 64; k0 += 4) {
            f4 a[4];
            #pragma unroll
            for (int i = 0; i < 4; ++i)
                a[i] = *(const f4*)(Ab + i * 128 + h * 64 + k0);  // 16-lane bcast
            f4 wl[4], wh[4];
            #pragma unroll
            for (int kk = 0; kk < 4; ++kk) {
                wl[kk] = *(const f4*)&wsh[(k0 + kk) * 128 + tx * 4];
                wh[kk] = *(const f4*)&wsh[(k0 + kk) * 128 + 64 + tx * 4];
            }
            #pragma unroll
            for (int i = 0; i < 4; ++i)
                #pragma unroll
                for (int kk = 0; kk < 4; ++kk)
                    #pragma unroll
                    for (int j = 0; j < 4; ++j) {
                        acc[i][j]     = fmaf(a[i][kk], wl[kk][j], acc[i][j]);
                        acc[i][4 + j] = fmaf(a[i][kk], wh[kk][j], acc[i][4 + j]);
                    }
        }
    }

    #pragma unroll
    for (int i = 0; i < 4; ++i) {
        size_t row = (size_t)rowBase + ty * 4 + i;
        f4 lo = {acc[i][0], acc[i][1], acc[i][2], acc[i][3]};
        f4 hi = {acc[i][4], acc[i][5], acc[i][6], acc[i][7]};
        *(f4*)&C[row * 128 + tx * 4]      = lo;
        *(f4*)&C[row * 128 + 64 + tx * 4] = hi;
    }
}

// Projections feeding selection + Wv@Wo fold + Wk_token transpose + cnt zero.
// kT projection is GONE (algebraic fold): token scores use q2 = q_tok @ Wk^T
// against RAW token_keys. 140 blocks.
__global__ __launch_bounds__(256) void proj_all(const float* __restrict__ queries,
                                                const float* __restrict__ stat_keys,
                                                const float* __restrict__ Wq_stat,
                                                const float* __restrict__ Wq_token,
                                                const float* __restrict__ Wk_stat,
                                                const float* __restrict__ Wk_token,
                                                const float* __restrict__ Wv,
                                                const float* __restrict__ Wo,
                                                float* __restrict__ q_stat,
                                                float* __restrict__ q_tok,
                                                float* __restrict__ k_stat,
                                                float* __restrict__ M_vo,
                                                float* __restrict__ WkT,
                                                int* __restrict__ cnt)
{
    __shared__ float wsh[64 * 128];      // 32 KB: one k-half of W
    const int bi = blockIdx.x;
    if (bi < 64)         proj_tile4_lds(queries,   Wq_stat,  q_stat, bi * 64,        threadIdx.x, wsh);
    else if (bi < 128)   proj_tile4_lds(queries,   Wq_token, q_tok, (bi - 64) * 64,  threadIdx.x, wsh);
    else if (bi < 136)   proj_tile4_lds(stat_keys, Wk_stat,  k_stat,(bi - 128) * 64, threadIdx.x, wsh);
    else if (bi < 138)   proj_tile4_lds(Wv,        Wo,       M_vo,  (bi - 136) * 64, threadIdx.x, wsh);
    else if (bi == 138) {
        // WkT[d][e] = Wk_token[e][d]
        #pragma unroll
        for (int i2 = 0; i2 < 16; ++i2) {
            int idx = i2 * 256 + threadIdx.x;    // f4 index 0..4095
            int e  = idx >> 5;
            int d4 = idx & 31;
            f4 v = *(const f4*)(Wk_token + (size_t)e * 128 + d4 * 4);
            WkT[(size_t)(d4 * 4 + 0) * 128 + e] = v[0];
            WkT[(size_t)(d4 * 4 + 1) * 128 + e] = v[1];
            WkT[(size_t)(d4 * 4 + 2) * 128 + e] = v[2];
            WkT[(size_t)(d4 * 4 + 3) * 128 + e] = v[3];
        }
    } else {
        for (int i = threadIdx.x; i < BB * SN; i += 256) cnt[i] = 0;
    }
}

// q2 = q_tok @ WkT (needs proj_all done -> separate launch). 64 blocks.
__global__ __launch_bounds__(256) void proj_q2(const float* __restrict__ q_tok,
                                               const float* __restrict__ WkT,
                                               float* __restrict__ q2)
{
    __shared__ float wsh[64 * 128];
    proj_tile4_lds(q_tok, WkT, q2, blockIdx.x * 64, threadIdx.x, wsh);
}

// ---------------------------------------------------------------------------
// Stat level + binning fused (R12-proven). Unbinned (wv==0) pids get their
// pvw row zeroed here (tok_pv3 clamps stale pvt tokens).
// ---------------------------------------------------------------------------
__global__ __launch_bounds__(64, 4) void stat_topk(const float* __restrict__ qs,
                                                   const float* __restrict__ ks,
                                                   const int* __restrict__ vlen,
                                                   int* __restrict__ sel_i,
                                                   float* __restrict__ sel_w,
                                                   int* __restrict__ cnt,
                                                   int* __restrict__ list,
                                                   float* __restrict__ pvw)
{
    const int bq   = blockIdx.x;
    const int b    = bq >> 9;
    const int lane = threadIdx.x;

    const f4* q4 = (const f4*)(qs + (size_t)bq * 128);
    const f4* k4 = (const f4*)(ks + (size_t)(b * SN + lane) * 128);
    float acc = 0.f;
    #pragma unroll 8
    for (int kk = 0; kk < 32; ++kk) {
        f4 q = q4[kk];
        f4 k = k4[kk];
        acc = fmaf(q[0], k[0], acc);
        acc = fmaf(q[1], k[1], acc);
        acc = fmaf(q[2], k[2], acc);
        acc = fmaf(q[3], k[3], acc);
    }
    float score = acc * SCALE;
    if (lane >= vlen[b]) score = NEGBIG;

    float work = score;
    float tv[STAT_K];
    int   ti[STAT_K];
    #pragma unroll
    for (int j = 0; j < STAT_K; ++j) {
        float m = work;
        #pragma unroll
        for (int off = 32; off > 0; off >>= 1) m = fmaxf(m, __shfl_xor(m, off));
        unsigned long long ball = __ballot(work == m);
        int L = __ffsll(ball) - 1;     // lowest index wins ties
        tv[j] = m;
        ti[j] = L;
        if (lane == L) work = NINF;
    }

    float w[STAT_K];
    float Z = 0.f;
    #pragma unroll
    for (int j = 0; j < STAT_K; ++j) { w[j] = expf(tv[j] - tv[0]); Z += w[j]; }
    float invZ = 1.f / Z;

    if (lane < STAT_K) {
        float wv = w[lane] * invZ;
        int pid = bq * STAT_K + lane;
        sel_i[pid] = ti[lane];
        sel_w[pid] = wv;
        if (wv != 0.f) {                         // sw==0: exactly-zero contribution
            int s  = ti[lane];
            int bs = b * SN + s;
            int pos = atomicAdd(&cnt[bs], 1);
            list[bs * 512 + pos] = (bq & 511) | (lane << 16);
        } else {
            #pragma unroll
            for (int j = 0; j < TOK_K; ++j)      // never written downstream: zero
                pvw[(size_t)pid * TOK_K + j] = 0.f;
        }
    }
}

// ---------------------------------------------------------------------------
// K1 (fused): token scores + EXACT top-16 + softmax weights vs RAW token_keys
// via q2 (kT fold). NEW: per-wave early-out — waves whose 16-slot range is
// entirely clamp-duplicate (q0+16*wid >= nq) stage + barrier but skip the
// GEMM, selection, and writes (~2x VALU work removed at avg nq=64; dup
// writes were byte-identical anyway). Barriers stay block-uniform.
// ---------------------------------------------------------------------------
__global__ __launch_bounds__(512) void tok_score_sel(const float* __restrict__ q2,
                                                     const float* __restrict__ token_keys,
                                                     const int* __restrict__ cnt,
                                                     const int* __restrict__ list,
                                                     const float* __restrict__ sel_w,
                                                     int* __restrict__ pvt,
                                                     float* __restrict__ pvw)
{
    const int bin   = blockIdx.x & 511;
    const int chunk = blockIdx.x >> 9;   // 0..3
    const int b  = bin & 7;              // batch fast -> XCD spread
    const int s  = bin >> 3;
    const int bs = b * SN + s;
    const int nq = cnt[bs];
    const int q0 = chunk * 128;
    if (q0 >= nq) return;                // block-uniform early out (pre-barrier)

    const int tid  = threadIdx.x;
    const int tx   = tid & 15;           // token-cols
    const int ty   = tid >> 4;           // 0..31, pair-slots q0+ty*4..+3
    const int lane = tid & 63;
    const int g    = lane >> 4;          // 16-lane group within wave
    const int wid  = tid >> 6;           // wave id 0..7

    // wave-uniform: does this wave own any REAL (non-duplicate) pair?
    const bool active = (q0 + wid * 16) < nq;

    int pid[4];
    float swp[4];
    const float* Ab[4];
    #pragma unroll
    for (int i = 0; i < 4; ++i) {
        int e  = list[bs * 512 + min(q0 + ty * 4 + i, nq - 1)];  // clamp: dup pair
        int q  = e & 0xffff;
        int si = (e >> 16) & 7;
        pid[i] = ((b << 9) + q) * 8 + si;
        swp[i] = sel_w[pid[i]];
        Ab[i]  = q2 + ((size_t)(b << 9) + q) * 128;
    }
    const float* kb = token_keys + ((size_t)bs << 14);   // raw [t][d] block

    __shared__ float ksh[64 * 128];      // 32 KB: one e-half, transposed [e][t]

    float acc[4][8];
    #pragma unroll
    for (int i = 0; i < 4; ++i)
        #pragma unroll
        for (int j = 0; j < 8; ++j) acc[i][j] = 0.f;

    const int st   = tid & 127;          // staging token
    const int dgrp = tid >> 7;           // 0..3 (wave-uniform)

    for (int h = 0; h < 2; ++h) {
        __syncthreads();                 // protect prior-half reads
        {
            const float* src = kb + (size_t)st * 128 + h * 64 + dgrp * 16;
            #pragma unroll
            for (int it2 = 0; it2 < 4; ++it2) {
                f4 v = *(const f4*)(src + it2 * 4);
                int dc = dgrp * 16 + it2 * 4;
                ksh[(dc + 0) * 128 + st] = v[0];   // banks: t%32, 2-way = free
                ksh[(dc + 1) * 128 + st] = v[1];
                ksh[(dc + 2) * 128 + st] = v[2];
                ksh[(dc + 3) * 128 + st] = v[3];
            }
        }
        __syncthreads();

        if (active) {                    // wave-uniform; no barrier inside
            #pragma unroll 2
            for (int k0 = 0; k0 < 64; k0 += 4) {
                f4 a[4];
                #pragma unroll
                for (int i = 0; i < 4; ++i)
                    a[i] = *(const f4*)(Ab[i] + h * 64 + k0);  // 16-lane bcast
                f4 wl[4], wh[4];
                #pragma unroll
                for (int kk = 0; kk < 4; ++kk) {
                    wl[kk] = *(const f4*)&ksh[(k0 + kk) * 128 + tx * 4];
                    wh[kk] = *(const f4*)&ksh[(k0 + kk) * 128 + 64 + tx * 4];
                }
                #pragma unroll
                for (int i = 0; i < 4; ++i)
                    #pragma unroll
                    for (int kk = 0; kk < 4; ++kk)
                        #pragma unroll
                        for (int j = 0; j < 4; ++j) {
                            acc[i][j]     = fmaf(a[i][kk], wl[kk][j], acc[i][j]);
                            acc[i][4 + j] = fmaf(a[i][kk], wh[kk][j], acc[i][4 + j]);
                        }
            }
        }
    }

    if (!active) return;                 // after all barriers

    // ---- exact in-register top-16 + softmax, 4 pids interleaved (R17) ----
    float s8[4][8];
    #pragma unroll
    for (int i = 0; i < 4; ++i)
        #pragma unroll
        for (int j = 0; j < 8; ++j) s8[i][j] = acc[i][j] * SCALE;

    float m0[4], myM[4];
    int   myT[4];
    #pragma unroll
    for (int i = 0; i < 4; ++i) { m0[i] = 0.f; myM[i] = 0.f; myT[i] = 0; }

    for (int it = 0; it < 16; ++it) {
        #pragma unroll
        for (int i = 0; i < 4; ++i) {
            // exact fp32 group max (tree + 4-step shfl, stays in 16-lane group)
            float v01 = fmaxf(s8[i][0], s8[i][1]);
            float v23 = fmaxf(s8[i][2], s8[i][3]);
            float v45 = fmaxf(s8[i][4], s8[i][5]);
            float v67 = fmaxf(s8[i][6], s8[i][7]);
            float m = fmaxf(fmaxf(v01, v23), fmaxf(v45, v67));
            #pragma unroll
            for (int off = 8; off > 0; off >>= 1) m = fmaxf(m, __shfl_xor(m, off));

            // per-lane lowest hit slot in each half (descending scan)
            int jlo = 4, jhi = 4;                     // 4 = no hit
            #pragma unroll
            for (int j = 3; j >= 0; --j) jlo = (s8[i][j]     == m) ? j : jlo;
            #pragma unroll
            for (int j = 3; j >= 0; --j) jhi = (s8[i][4 + j] == m) ? j : jhi;

            // exact lowest-t via ballots: lower half beats upper; lowest lane
            // = lowest t (lane tx owns t = 4tx..4tx+3 / 64+4tx..64+4tx+3)
            u64 blo = __ballot(jlo < 4);
            u64 bhi = __ballot(jhi < 4);
            unsigned mlo = (unsigned)((blo >> (g * 16)) & 0xFFFFu);
            unsigned mhi = (unsigned)((bhi >> (g * 16)) & 0xFFFFu);
            bool lo = (mlo != 0);
            unsigned msel = lo ? mlo : mhi;
            int L = __ffs(msel) - 1;                  // winner lane in group
            int jsel = lo ? jlo : jhi;
            int jwin = __shfl(jsel, g * 16 + L);      // winner's slot-in-half
            int tstar = (lo ? 0 : 64) + 4 * L + jwin;

            m0[i] = (it == 0) ? m : m0[i];
            bool rec = (tx == it);
            myT[i] = rec ? tstar : myT[i];
            myM[i] = rec ? m : myM[i];

            // branch-free knock of the unique winning slot
            int slot = (lo ? 0 : 4) + jwin;           // uniform within group
            bool winlane = (tx == L);
            #pragma unroll
            for (int j = 0; j < 8; ++j)
                s8[i][j] = (winlane && slot == j) ? NINF : s8[i][j];
        }
    }

    #pragma unroll
    for (int i = 0; i < 4; ++i) {
        float myE = expf(myM[i] - m0[i]);      // exact
        float Z = myE;
        #pragma unroll
        for (int off = 8; off > 0; off >>= 1) Z += __shfl_xor(Z, off);
        float cs = swp[i] / Z;                 // fold stat weight in

        pvt[(size_t)pid[i] * TOK_K + tx] = myT[i];   // dup pids: identical data
        pvw[(size_t)pid[i] * TOK_K + tx] = myE * cs;
    }
}

// ---------------------------------------------------------------------------
// K3 (fused): PV accumulate on RAW values + output projection with M_vo.
// One wave per (b,q): PV row in registers -> LDS (same-wave, in-order) ->
// row @ M_vo (L1-resident) -> direct store to d_out. No atomics.
// t clamped to [0,127]: stale pvt for unbinned pids is harmless (pvw==0).
// ---------------------------------------------------------------------------
__global__ __launch_bounds__(256) void tok_pv3(const float* __restrict__ values,
                                               const int* __restrict__ sel_i,
                                               const int* __restrict__ pvt,
                                               const float* __restrict__ pvw,
                                               const float* __restrict__ M_vo,
                                               float* __restrict__ out)
{
    const int wid  = threadIdx.x >> 6;
    const int bq   = blockIdx.x * 4 + wid;
    const int lane = threadIdx.x & 63;
    const int b    = bq >> 9;

    float o0 = 0.f, o1 = 0.f;
    #pragma unroll
    for (int si = 0; si < STAT_K; ++si) {
        const int pid = bq * STAT_K + si;
        const int s   = sel_i[pid];
        const float* vb = values + ((size_t)(b * SN + s) << 14);
        const int*   tp = pvt + (size_t)pid * TOK_K;
        const float* wp = pvw + (size_t)pid * TOK_K;
        #pragma unroll
        for (int j = 0; j < TOK_K; ++j) {
            int   t = tp[j] & 127;           // wave-uniform; clamp stale entries
            float w = wp[j];                 // ==0 for skipped pids: exact no-op
            f2 x = *(const f2*)(vb + (size_t)t * 128 + lane * 2);
            o0 = fmaf(w, x[0], o0);
            o1 = fmaf(w, x[1], o1);
        }
    }

    __shared__ float pre[4][128];
    *(f2*)&pre[wid][lane * 2] = (f2){o0, o1};
    __asm__ __volatile__("" ::: "memory");
    __builtin_amdgcn_wave_barrier();        // same-wave LDS RAW: in-order pipe
    __asm__ __volatile__("" ::: "memory");

    float r0 = 0.f, r1 = 0.f;
    #pragma unroll 4
    for (int d = 0; d < 128; ++d) {
        float p = pre[wid][d];               // broadcast read
        f2 w = *(const f2*)(M_vo + (size_t)d * 128 + lane * 2);
        r0 = fmaf(p, w[0], r0);
        r1 = fmaf(p, w[1], r1);
    }
    *(f2*)&out[(size_t)bq * 128 + lane * 2] = (f2){r0, r1};
}

// ---------------------------------------------------------------------------
extern "C" void kernel_launch(void* const* d_in, const int* in_sizes, int n_in,
                              void* d_out, int out_size, void* d_ws, size_t ws_size,
                              hipStream_t stream)
{
    const float* queries    = (const float*)d_in[0];
    const float* stat_keys  = (const float*)d_in[1];
    const float* token_keys = (const float*)d_in[2];
    const float* values     = (const float*)d_in[3];
    const int*   vlen       = (const int*)d_in[4];
    const float* Wq_stat    = (const float*)d_in[5];
    const float* Wq_token   = (const float*)d_in[6];
    const float* Wk_stat    = (const float*)d_in[7];
    const float* Wk_token   = (const float*)d_in[8];
    const float* Wv         = (const float*)d_in[9];
    const float* Wo         = (const float*)d_in[10];

    char* ws = (char*)d_ws;
    float* q_stat  = (float*)(ws);                 // 2 MB
    float* q_tok   = (float*)(ws + 2097152);       // 2 MB
    float* k_stat  = (float*)(ws + 4194304);       // 256 KB
    float* M_vo    = (float*)(ws + 4456448);       // 64 KB (Wv @ Wo)
    float* WkT     = (float*)(ws + 4521984);       // 64 KB (Wk_token^T)
    int*   sel_i   = (int*)  (ws + 4587520);       // 128 KB
    float* sel_w   = (float*)(ws + 4718592);       // 128 KB
    float* q2      = (float*)(ws + 4849664);       // 2 MB (q_tok @ Wk^T)
    int*   pvt     = (int*)  (ws + 6946816);       // 2 MB
    float* pvw     = (float*)(ws + 9043968);       // 2 MB
    int*   list    = (int*)  (ws + 11141120);      // 1 MB
    int*   cnt     = (int*)  (ws + 12189696);      // 2 KB   (total ~12.2 MB)

    // Projections feeding selection + M_vo fold + Wk^T + cnt zeroing
    proj_all<<<140, 256, 0, stream>>>(queries, stat_keys,
                                      Wq_stat, Wq_token, Wk_stat, Wk_token, Wv, Wo,
                                      q_stat, q_tok, k_stat, M_vo, WkT, cnt);

    // q2 = q_tok @ Wk^T (token-score fold; needs proj_all outputs)
    proj_q2<<<64, 256, 0, stream>>>(q_tok, WkT, q2);

    // Stat-level top-8 + weights + bin append + pvw zeroing (fused)
    stat_topk<<<BB * QN, 64, 0, stream>>>(q_stat, k_stat, vlen, sel_i, sel_w,
                                          cnt, list, pvw);

    // K1: token scores vs RAW token_keys (LDS transpose-staged, 8-wave
    // blocks, per-wave dup-work early-out)
    tok_score_sel<<<2048, 512, 0, stream>>>(q2, token_keys, cnt, list, sel_w,
                                            pvt, pvw);

    // K3: PV + output projection fused, one wave per (b,q), direct to d_out
    tok_pv3<<<BB * QN / 4, 256, 0, stream>>>(values, sel_i, pvt, pvw, M_vo,
                                             (float*)d_out);
}